// Round 1
// baseline (2330.469 us; speedup 1.0000x reference)
//
#include <hip/hip_runtime.h>

// ---- problem constants ----
constexpr int Bc = 4;
constexpr int Cc = 2048;
constexpr int Sc = 1024;     // H*W = 32*32
constexpr int Ntok = 4096;   // B*S
constexpr int Ec = 768;
constexpr int E3 = 2304;
constexpr int NHEAD = 12;
constexpr int DHEAD = 64;
constexpr int GHEAD = 4;
constexpr int DGAT = 192;

// ============ LN1 over C=2048 (tok = x transposed), writes n1t[c][n] ============
__global__ __launch_bounds__(256) void k_ln1(const float* __restrict__ x,
    const float* __restrict__ g, const float* __restrict__ bt,
    float* __restrict__ n1t) {
  int blk = blockIdx.x;            // 256 blocks: b (4) * 64 s-tiles
  int b = blk >> 6;
  int s0 = (blk & 63) << 4;        // 16 s per block
  int sl = threadIdx.x & 15;
  int cl = threadIdx.x >> 4;       // 0..15
  int s = s0 + sl;
  const float* xb = x + (size_t)b * Cc * Sc + s;
  float sum = 0.f, ss = 0.f;
  for (int c = cl; c < Cc; c += 16) {
    float v = xb[(size_t)c * Sc];
    sum += v; ss += v * v;
  }
  __shared__ float rs0[16][17], rs1[16][17];
  __shared__ float mean_s[16], rstd_s[16];
  rs0[cl][sl] = sum; rs1[cl][sl] = ss;
  __syncthreads();
  if (cl == 0) {
    float a = 0.f, q = 0.f;
    for (int i = 0; i < 16; i++) { a += rs0[i][sl]; q += rs1[i][sl]; }
    float mean = a / Cc;
    float var = q / Cc - mean * mean;
    mean_s[sl] = mean; rstd_s[sl] = rsqrtf(var + 1e-5f);
  }
  __syncthreads();
  float mean = mean_s[sl], rstd = rstd_s[sl];
  float* outb = n1t + (size_t)b * Sc + s;   // n1t[c*Ntok + b*S + s]
  for (int c = cl; c < Cc; c += 16) {
    float v = xb[(size_t)c * Sc];
    outb[(size_t)c * Ntok] = (v - mean) * rstd * g[c] + bt[c];
  }
}

// ============ f32 tiled GEMM 128x128x16, 256 thr, 8x8/thread ============
// AKM=1: A stored [K][M]; AKM=0: A row-major [M][K]. B row-major [K][N].
// EPI: 0 none, 1 +bias, 2 +bias+residual, 3 +bias+gelu(exact)
template<int AKM, int EPI>
__global__ __launch_bounds__(256) void gemm_f32(const float* __restrict__ A,
    const float* __restrict__ Bm, const float* __restrict__ bias,
    const float* __restrict__ res, float* __restrict__ Cm,
    int M, int Nn, int K) {
  constexpr int BM = 128, BN = 128, BK = 16;
  __shared__ float As[BK][BM + 4];
  __shared__ float Bs[BK][BN + 4];
  int bn = blockIdx.x, bm = blockIdx.y;
  int tid = threadIdx.x;
  int tr = tid >> 4, tc = tid & 15;
  int m0 = bm * BM, n0 = bn * BN;
  float acc[8][8] = {};
  for (int k0 = 0; k0 < K; k0 += BK) {
    if (AKM) {
#pragma unroll
      for (int i = 0; i < 8; i++) {
        int idx = tid + 256 * i; int kk = idx >> 7; int m = idx & 127;
        As[kk][m] = A[(size_t)(k0 + kk) * M + m0 + m];
      }
    } else {
#pragma unroll
      for (int i = 0; i < 8; i++) {
        int idx = tid + 256 * i; int r = idx >> 4; int c = idx & 15;
        As[c][r] = A[(size_t)(m0 + r) * K + k0 + c];
      }
    }
#pragma unroll
    for (int i = 0; i < 8; i++) {
      int idx = tid + 256 * i; int kk = idx >> 7; int n = idx & 127;
      Bs[kk][n] = Bm[(size_t)(k0 + kk) * Nn + n0 + n];
    }
    __syncthreads();
#pragma unroll
    for (int kk = 0; kk < BK; kk++) {
      float a[8], b[8];
#pragma unroll
      for (int i = 0; i < 8; i++) a[i] = As[kk][tr * 8 + i];
#pragma unroll
      for (int j = 0; j < 8; j++) b[j] = Bs[kk][tc * 8 + j];
#pragma unroll
      for (int i = 0; i < 8; i++)
#pragma unroll
        for (int j = 0; j < 8; j++) acc[i][j] += a[i] * b[j];
    }
    __syncthreads();
  }
#pragma unroll
  for (int i = 0; i < 8; i++) {
    int m = m0 + tr * 8 + i;
#pragma unroll
    for (int j = 0; j < 8; j++) {
      int n = n0 + tc * 8 + j;
      float c = acc[i][j];
      if (EPI != 0) c += bias[n];
      if (EPI == 2) c += res[(size_t)m * Nn + n];
      if (EPI == 3) c = 0.5f * c * (1.f + erff(c * 0.70710678118f));
      Cm[(size_t)m * Nn + n] = c;
    }
  }
}

// ============ MHSA: per (b, head, 16-row q-tile), full scores in LDS ============
__global__ __launch_bounds__(256) void k_attn(const float* __restrict__ qkv,
    float* __restrict__ o) {
  int qt = blockIdx.x, h = blockIdx.y, b = blockIdx.z;
  int tid = threadIdx.x;
  __shared__ float qs[16][64];
  __shared__ float sc[16][1024];
  __shared__ float kv[64][68];
  int q0 = qt * 16;
  const float* base = qkv + (size_t)b * Sc * E3;
  for (int i = tid; i < 16 * 64; i += 256) {
    int r = i >> 6, d = i & 63;
    qs[r][d] = base[(size_t)(q0 + r) * E3 + h * 64 + d];
  }
  int qi = tid >> 4;
  int lane = tid & 15;
  const float scale = 0.125f;  // 1/sqrt(64)
  // scores
  for (int kt = 0; kt < 16; kt++) {
    __syncthreads();
    for (int i = tid; i < 64 * 64; i += 256) {
      int r = i >> 6, d = i & 63;
      kv[r][d] = base[(size_t)(kt * 64 + r) * E3 + Ec + h * 64 + d];
    }
    __syncthreads();
#pragma unroll
    for (int rep = 0; rep < 4; rep++) {
      int kj = lane + rep * 16;
      float acc = 0.f;
#pragma unroll
      for (int d = 0; d < 64; d += 4) {
        float4 qv = *(const float4*)&qs[qi][d];
        float4 kk = *(const float4*)&kv[kj][d];
        acc += qv.x * kk.x + qv.y * kk.y + qv.z * kk.z + qv.w * kk.w;
      }
      sc[qi][kt * 64 + kj] = acc * scale;
    }
  }
  __syncthreads();
  // softmax per row (16 lanes per row)
  float mx = -1e30f;
  for (int j = lane; j < 1024; j += 16) mx = fmaxf(mx, sc[qi][j]);
#pragma unroll
  for (int off = 8; off > 0; off >>= 1) mx = fmaxf(mx, __shfl_xor(mx, off, 16));
  float sum = 0.f;
  for (int j = lane; j < 1024; j += 16) {
    float e = expf(sc[qi][j] - mx);
    sc[qi][j] = e; sum += e;
  }
#pragma unroll
  for (int off = 8; off > 0; off >>= 1) sum += __shfl_xor(sum, off, 16);
  float inv = 1.f / sum;
  for (int j = lane; j < 1024; j += 16) sc[qi][j] *= inv;
  // o = att @ v ; thread owns (qi, d0..d0+3)
  int d0 = lane * 4;
  float a0 = 0, a1 = 0, a2 = 0, a3 = 0;
  for (int kt = 0; kt < 16; kt++) {
    __syncthreads();
    for (int i = tid; i < 64 * 64; i += 256) {
      int r = i >> 6, d = i & 63;
      kv[r][d] = base[(size_t)(kt * 64 + r) * E3 + 2 * Ec + h * 64 + d];
    }
    __syncthreads();
#pragma unroll 8
    for (int kj = 0; kj < 64; kj++) {
      float p = sc[qi][kt * 64 + kj];
      float4 vv = *(const float4*)&kv[kj][d0];
      a0 += p * vv.x; a1 += p * vv.y; a2 += p * vv.z; a3 += p * vv.w;
    }
  }
  float* orow = o + (size_t)(b * Sc + q0 + qi) * Ec + h * 64 + d0;
  orow[0] = a0; orow[1] = a1; orow[2] = a2; orow[3] = a3;
}

// ============ LN over rows of E=768. MODE 0: plain out. MODE 1: +res, transposed out ============
template<int MODE>
__global__ __launch_bounds__(256) void k_lnrow(const float* __restrict__ in,
    const float* __restrict__ res, const float* __restrict__ g,
    const float* __restrict__ bt, float* __restrict__ out) {
  int row = blockIdx.x;
  int tid = threadIdx.x;
  __shared__ float buf[Ec];
  __shared__ float rsum[4], rss[4];
  float sum = 0.f, ss = 0.f;
  for (int i = tid; i < Ec; i += 256) {
    float v = in[(size_t)row * Ec + i];
    if (MODE == 1) v += res[(size_t)row * Ec + i];
    buf[i] = v; sum += v; ss += v * v;
  }
#pragma unroll
  for (int off = 32; off > 0; off >>= 1) {
    sum += __shfl_xor(sum, off); ss += __shfl_xor(ss, off);
  }
  if ((tid & 63) == 0) { rsum[tid >> 6] = sum; rss[tid >> 6] = ss; }
  __syncthreads();
  sum = rsum[0] + rsum[1] + rsum[2] + rsum[3];
  ss = rss[0] + rss[1] + rss[2] + rss[3];
  float mean = sum / Ec;
  float rstd = rsqrtf(ss / Ec - mean * mean + 1e-5f);
  if (MODE == 0) {
    for (int i = tid; i < Ec; i += 256)
      out[(size_t)row * Ec + i] = (buf[i] - mean) * rstd * g[i] + bt[i];
  } else {
    int b = row >> 10, s = row & 1023;
    for (int i = tid; i < Ec; i += 256)
      out[((size_t)b * Ec + i) * Sc + s] = (buf[i] - mean) * rstd * g[i] + bt[i];
  }
}

// ============ per-node attention coefficients a_s, a_d ============
__global__ __launch_bounds__(256) void k_asd(const float* __restrict__ hN,
    const float* __restrict__ att_src, const float* __restrict__ att_dst,
    float* __restrict__ a_s, float* __restrict__ a_d) {
  int n = blockIdx.x * 4 + (threadIdx.x >> 6);
  int lane = threadIdx.x & 63;
  const float* hrow = hN + (size_t)n * Ec;
#pragma unroll
  for (int h = 0; h < GHEAD; h++) {
    float ps = 0.f, pd = 0.f;
    for (int d = lane; d < DGAT; d += 64) {
      float v = hrow[h * DGAT + d];
      ps += v * att_src[h * DGAT + d];
      pd += v * att_dst[h * DGAT + d];
    }
#pragma unroll
    for (int off = 32; off > 0; off >>= 1) {
      ps += __shfl_xor(ps, off); pd += __shfl_xor(pd, off);
    }
    if (lane == 0) { a_s[n * GHEAD + h] = ps; a_d[n * GHEAD + h] = pd; }
  }
}

// ============ GAT stencil: softmax over (valid 8-nbrs + self), aggregate, elu, residual ============
__global__ __launch_bounds__(256) void k_gat(const float* __restrict__ hN,
    const float* __restrict__ a_s, const float* __restrict__ a_d,
    const float* __restrict__ x_attn, const float* __restrict__ gat_b,
    float* __restrict__ x_after) {
  int n = blockIdx.x;
  int b = n >> 10, s = n & 1023, r = s >> 5, c = s & 31;
  __shared__ int nbr[9];
  __shared__ float alpha[GHEAD][9];
  int tid = threadIdx.x;
  if (tid < 9) {
    int dr = tid / 3 - 1, dc = tid % 3 - 1;
    int rr = r + dr, cc = c + dc;
    int ok = (rr >= 0 && rr < 32 && cc >= 0 && cc < 32);
    // reference quirk: anti-diagonal edges exist only when upper endpoint's column <= W-2
    if (dr == -1 && dc == 1 && cc == 31) ok = 0;   // upper endpoint (rr,cc)
    if (dr == 1 && dc == -1 && c == 31) ok = 0;    // upper endpoint (r,c)
    nbr[tid] = ok ? ((b << 10) + (rr << 5) + cc) : -1;
  }
  __syncthreads();
  if (tid < GHEAD) {
    int h = tid;
    float ad = a_d[n * GHEAD + h];
    float ev[9]; float m = -1e30f;
#pragma unroll
    for (int j = 0; j < 9; j++) {
      if (nbr[j] >= 0) {
        float e = a_s[nbr[j] * GHEAD + h] + ad;
        e = e > 0.f ? e : 0.2f * e;   // leaky_relu 0.2
        ev[j] = e; m = fmaxf(m, e);
      } else ev[j] = -1e30f;
    }
    float den = 0.f;
#pragma unroll
    for (int j = 0; j < 9; j++) {
      float x = (nbr[j] >= 0) ? expf(ev[j] - m) : 0.f;
      ev[j] = x; den += x;
    }
    float inv = 1.f / den;
#pragma unroll
    for (int j = 0; j < 9; j++) alpha[h][j] = ev[j] * inv;
  }
  __syncthreads();
  for (int e = tid; e < Ec; e += 256) {
    int h = e / DGAT;
    float acc = 0.f;
#pragma unroll
    for (int j = 0; j < 9; j++) {
      int nj = nbr[j];
      if (nj >= 0) acc += alpha[h][j] * hN[(size_t)nj * Ec + e];
    }
    float v = acc + gat_b[e];
    v = v > 0.f ? v : expf(v) - 1.f;   // elu
    x_after[(size_t)n * Ec + e] = x_attn[(size_t)n * Ec + e] + v;
  }
}

extern "C" void kernel_launch(void* const* d_in, const int* in_sizes, int n_in,
                              void* d_out, int out_size, void* d_ws, size_t ws_size,
                              hipStream_t stream) {
  (void)in_sizes; (void)n_in; (void)out_size; (void)ws_size;
  const float* x      = (const float*)d_in[0];
  const float* ln1_g  = (const float*)d_in[1];
  const float* ln1_b  = (const float*)d_in[2];
  const float* proj_w = (const float*)d_in[3];
  const float* proj_b = (const float*)d_in[4];
  const float* wqkv   = (const float*)d_in[5];
  const float* bqkv   = (const float*)d_in[6];
  const float* wo     = (const float*)d_in[7];
  const float* bo     = (const float*)d_in[8];
  const float* ln2_g  = (const float*)d_in[9];
  const float* ln2_b  = (const float*)d_in[10];
  const float* gp_w   = (const float*)d_in[11];
  const float* gp_b   = (const float*)d_in[12];
  const float* gat_w  = (const float*)d_in[13];
  const float* att_src= (const float*)d_in[14];
  const float* att_dst= (const float*)d_in[15];
  const float* gat_b  = (const float*)d_in[16];
  const float* ln3_g  = (const float*)d_in[17];
  const float* ln3_b  = (const float*)d_in[18];
  const float* mlp_w1 = (const float*)d_in[19];
  const float* mlp_b1 = (const float*)d_in[20];
  const float* mlp_w2 = (const float*)d_in[21];
  const float* mlp_b2 = (const float*)d_in[22];
  const float* fn_g   = (const float*)d_in[23];
  const float* fn_b   = (const float*)d_in[24];
  float* out = (float*)d_out;

  float* ws = (float*)d_ws;
  float* n1t    = ws;                   // [2048][4096]  (reused later as qkv)
  float* qkv    = ws;                   // [4096][2304]
  float* v_in   = ws + 9437184;         // [4096][768]   (later n3)
  float* o_buf  = ws + 12582912;        // [4096][768]   (later x_after)
  float* x_attn = ws + 15728640;        // [4096][768]
  float* n2     = ws + 18874368;        // [4096][768]   (later mlp hidden)
  float* gbuf   = ws + 22020096;        // [4096][768]   (later mlp out)
  float* hN     = ws + 25165824;        // [4096][768]
  float* a_s    = ws + 28311552;        // [4096][4]
  float* a_d    = a_s + 16384;          // [4096][4]

  // 1) LN over C + transpose-store
  k_ln1<<<256, 256, 0, stream>>>(x, ln1_g, ln1_b, n1t);
  // 2) v_in = n1 @ proj_w + proj_b   (A in [K][M] layout)
  gemm_f32<1, 1><<<dim3(Ec / 128, Ntok / 128), 256, 0, stream>>>(
      n1t, proj_w, proj_b, nullptr, v_in, Ntok, Ec, Cc);
  // 3) qkv = v_in @ wqkv + bqkv  (writes over n1t region)
  gemm_f32<0, 1><<<dim3(E3 / 128, Ntok / 128), 256, 0, stream>>>(
      v_in, wqkv, bqkv, nullptr, qkv, Ntok, E3, Ec);
  // 4) attention
  k_attn<<<dim3(64, NHEAD, Bc), 256, 0, stream>>>(qkv, o_buf);
  // 5) x_attn = v_in + o @ wo + bo
  gemm_f32<0, 2><<<dim3(Ec / 128, Ntok / 128), 256, 0, stream>>>(
      o_buf, wo, bo, v_in, x_attn, Ntok, Ec, Ec);
  // 6) n2 = LN(x_attn)
  k_lnrow<0><<<Ntok, 256, 0, stream>>>(x_attn, nullptr, ln2_g, ln2_b, n2);
  // 7) g = n2 @ gp_w + gp_b
  gemm_f32<0, 1><<<dim3(Ec / 128, Ntok / 128), 256, 0, stream>>>(
      n2, gp_w, gp_b, nullptr, gbuf, Ntok, Ec, Ec);
  // 8) hN = g @ gat_w  (no bias)
  gemm_f32<0, 0><<<dim3(Ec / 128, Ntok / 128), 256, 0, stream>>>(
      gbuf, gat_w, nullptr, nullptr, hN, Ntok, Ec, Ec);
  // 9) a_s, a_d
  k_asd<<<Ntok / 4, 256, 0, stream>>>(hN, att_src, att_dst, a_s, a_d);
  // 10) GAT aggregate + elu + residual -> x_after (reuses o_buf)
  k_gat<<<Ntok, 256, 0, stream>>>(hN, a_s, a_d, x_attn, gat_b, o_buf);
  // 11) n3 = LN(x_after)  (reuses v_in)
  k_lnrow<0><<<Ntok, 256, 0, stream>>>(o_buf, nullptr, ln3_g, ln3_b, v_in);
  // 12) h1 = gelu(n3 @ mlp_w1 + mlp_b1)  (reuses n2)
  gemm_f32<0, 3><<<dim3(Ec / 128, Ntok / 128), 256, 0, stream>>>(
      v_in, mlp_w1, mlp_b1, nullptr, n2, Ntok, Ec, Ec);
  // 13) mlp = h1 @ mlp_w2 + mlp_b2  (reuses gbuf)
  gemm_f32<0, 1><<<dim3(Ec / 128, Ntok / 128), 256, 0, stream>>>(
      n2, mlp_w2, mlp_b2, nullptr, gbuf, Ntok, Ec, Ec);
  // 14) out = LN(n3 + mlp), transposed to [B,E,H,W]
  k_lnrow<1><<<Ntok, 256, 0, stream>>>(v_in, gbuf, fn_g, fn_b, out);
}

// Round 2
// 1204.023 us; speedup vs baseline: 1.9356x; 1.9356x over previous
//
#include <hip/hip_runtime.h>

// ---- problem constants ----
constexpr int Bc = 4;
constexpr int Cc = 2048;
constexpr int Sc = 1024;     // H*W = 32*32
constexpr int Ntok = 4096;   // B*S
constexpr int Ec = 768;
constexpr int E3 = 2304;
constexpr int NHEAD = 12;
constexpr int GHEAD = 4;
constexpr int DGAT = 192;

typedef __attribute__((ext_vector_type(8))) short short8_t;   // bf16x8 MFMA frag
typedef __attribute__((ext_vector_type(4))) short short4_t;
typedef __attribute__((ext_vector_type(4))) float f32x4;

__device__ inline unsigned short f2bf(float f) {
  unsigned int u = __builtin_bit_cast(unsigned int, f);
  u += 0x7FFFu + ((u >> 16) & 1u);     // RNE
  return (unsigned short)(u >> 16);
}

// ============ LN1 over C=2048 (tok = x transposed), writes n1t[c][n] ============
__global__ __launch_bounds__(256) void k_ln1(const float* __restrict__ x,
    const float* __restrict__ g, const float* __restrict__ bt,
    float* __restrict__ n1t) {
  int blk = blockIdx.x;            // 256 blocks: b (4) * 64 s-tiles
  int b = blk >> 6;
  int s0 = (blk & 63) << 4;        // 16 s per block
  int sl = threadIdx.x & 15;
  int cl = threadIdx.x >> 4;       // 0..15
  int s = s0 + sl;
  const float* xb = x + (size_t)b * Cc * Sc + s;
  float sum = 0.f, ss = 0.f;
  for (int c = cl; c < Cc; c += 16) {
    float v = xb[(size_t)c * Sc];
    sum += v; ss += v * v;
  }
  __shared__ float rs0[16][17], rs1[16][17];
  __shared__ float mean_s[16], rstd_s[16];
  rs0[cl][sl] = sum; rs1[cl][sl] = ss;
  __syncthreads();
  if (cl == 0) {
    float a = 0.f, q = 0.f;
    for (int i = 0; i < 16; i++) { a += rs0[i][sl]; q += rs1[i][sl]; }
    float mean = a / Cc;
    float var = q / Cc - mean * mean;
    mean_s[sl] = mean; rstd_s[sl] = rsqrtf(var + 1e-5f);
  }
  __syncthreads();
  float mean = mean_s[sl], rstd = rstd_s[sl];
  float* outb = n1t + (size_t)b * Sc + s;   // n1t[c*Ntok + b*S + s]
  for (int c = cl; c < Cc; c += 16) {
    float v = xb[(size_t)c * Sc];
    outb[(size_t)c * Ntok] = (v - mean) * rstd * g[c] + bt[c];
  }
}

// ============ f32 tiled GEMM 128x128x16, 256 thr, 8x8/thread ============
// AKM=1: A stored [K][M]; AKM=0: A row-major [M][K]. B row-major [K][N].
// EPI: 0 none, 1 +bias, 2 +bias+residual, 3 +bias+gelu(exact)
template<int AKM, int EPI>
__global__ __launch_bounds__(256) void gemm_f32(const float* __restrict__ A,
    const float* __restrict__ Bm, const float* __restrict__ bias,
    const float* __restrict__ res, float* __restrict__ Cm,
    int M, int Nn, int K) {
  constexpr int BM = 128, BN = 128, BK = 16;
  __shared__ float As[BK][BM + 4];
  __shared__ float Bs[BK][BN + 4];
  int bn = blockIdx.x, bm = blockIdx.y;
  int tid = threadIdx.x;
  int tr = tid >> 4, tc = tid & 15;
  int m0 = bm * BM, n0 = bn * BN;
  float acc[8][8] = {};
  for (int k0 = 0; k0 < K; k0 += BK) {
    if (AKM) {
#pragma unroll
      for (int i = 0; i < 8; i++) {
        int idx = tid + 256 * i; int kk = idx >> 7; int m = idx & 127;
        As[kk][m] = A[(size_t)(k0 + kk) * M + m0 + m];
      }
    } else {
#pragma unroll
      for (int i = 0; i < 8; i++) {
        int idx = tid + 256 * i; int r = idx >> 4; int c = idx & 15;
        As[c][r] = A[(size_t)(m0 + r) * K + k0 + c];
      }
    }
#pragma unroll
    for (int i = 0; i < 8; i++) {
      int idx = tid + 256 * i; int kk = idx >> 7; int n = idx & 127;
      Bs[kk][n] = Bm[(size_t)(k0 + kk) * Nn + n0 + n];
    }
    __syncthreads();
#pragma unroll
    for (int kk = 0; kk < BK; kk++) {
      float a[8], b[8];
#pragma unroll
      for (int i = 0; i < 8; i++) a[i] = As[kk][tr * 8 + i];
#pragma unroll
      for (int j = 0; j < 8; j++) b[j] = Bs[kk][tc * 8 + j];
#pragma unroll
      for (int i = 0; i < 8; i++)
#pragma unroll
        for (int j = 0; j < 8; j++) acc[i][j] += a[i] * b[j];
    }
    __syncthreads();
  }
#pragma unroll
  for (int i = 0; i < 8; i++) {
    int m = m0 + tr * 8 + i;
#pragma unroll
    for (int j = 0; j < 8; j++) {
      int n = n0 + tc * 8 + j;
      float c = acc[i][j];
      if (EPI != 0) c += bias[n];
      if (EPI == 2) c += res[(size_t)m * Nn + n];
      if (EPI == 3) c = 0.5f * c * (1.f + erff(c * 0.70710678118f));
      Cm[(size_t)m * Nn + n] = c;
    }
  }
}

// ============ MHSA via MFMA bf16, flash-style online softmax ============
// grid: (S/64, NHEAD, B), 256 threads = 4 waves; each wave owns 16 q-rows.
__global__ __launch_bounds__(256) void k_attn_mfma(const float* __restrict__ qkv,
    float* __restrict__ o) {
  __shared__ unsigned short Ks[64][72];   // bf16 [key][dh], pad->2-way-free b128 reads
  __shared__ unsigned short Vt[64][68];   // bf16 [dh][key], pad->b64 reads
  __shared__ float Pl[4][16][68];         // per-wave P scratch (C-layout -> A-layout)
  int qt = blockIdx.x, h = blockIdx.y, b = blockIdx.z;
  int tid = threadIdx.x;
  int w = tid >> 6, lane = tid & 63;
  int g = lane >> 4, l16 = lane & 15;
  const float* base  = qkv + (size_t)b * Sc * E3;
  const float* kbase = base + Ec + h * 64;
  const float* vbase = base + 2 * Ec + h * 64;
  int q0 = qt * 64 + w * 16;

  // Q fragments (A-layout: row=lane&15, k=(lane>>4)*8+e), pre-scaled by 1/sqrt(64)
  short8_t qf[2];
#pragma unroll
  for (int ks = 0; ks < 2; ks++) {
    const float* qp = base + (size_t)(q0 + l16) * E3 + h * 64 + ks * 32 + g * 8;
    short8_t f;
#pragma unroll
    for (int e = 0; e < 8; e++) f[e] = (short)f2bf(qp[e] * 0.125f);
    qf[ks] = f;
  }

  f32x4 o_acc[4] = {};
  float m_r[4] = {-1e30f, -1e30f, -1e30f, -1e30f};
  float l_r[4] = {};

  for (int kt = 0; kt < 16; kt++) {
    __syncthreads();
    // stage K tile (64 keys x 64 dh) as bf16
#pragma unroll
    for (int i = 0; i < 8; i++) {
      int idx = tid + i * 256;            // 64 rows x 32 float2
      int r = idx >> 5, c2 = (idx & 31) * 2;
      float2 kv2 = *(const float2*)(kbase + (size_t)(kt * 64 + r) * E3 + c2);
      *(unsigned int*)&Ks[r][c2] = (unsigned int)f2bf(kv2.x) | ((unsigned int)f2bf(kv2.y) << 16);
    }
    // stage V tile transposed: Vt[d][key]
#pragma unroll
    for (int i = 0; i < 8; i++) {
      int idx = tid + i * 256;            // 64 cols x 32 row-pairs
      int c = idx & 63, rp = idx >> 6;
      float va = vbase[(size_t)(kt * 64 + 2 * rp) * E3 + c];
      float vb = vbase[(size_t)(kt * 64 + 2 * rp + 1) * E3 + c];
      *(unsigned int*)&Vt[c][2 * rp] = (unsigned int)f2bf(va) | ((unsigned int)f2bf(vb) << 16);
    }
    __syncthreads();

    // S = Q @ K^T  (4 key-subtiles x 2 k-steps)
    f32x4 s_acc[4] = {};
#pragma unroll
    for (int nt = 0; nt < 4; nt++) {
#pragma unroll
      for (int ks = 0; ks < 2; ks++) {
        short8_t kf = *(const short8_t*)&Ks[nt * 16 + l16][ks * 32 + g * 8];
        s_acc[nt] = __builtin_amdgcn_mfma_f32_16x16x32_bf16(qf[ks], kf, s_acc[nt], 0, 0, 0);
      }
    }

    // online softmax; C-layout: row=(g*4+reg), col=l16+16*nt
#pragma unroll
    for (int r = 0; r < 4; r++) {
      float mx = fmaxf(fmaxf(s_acc[0][r], s_acc[1][r]), fmaxf(s_acc[2][r], s_acc[3][r]));
#pragma unroll
      for (int off = 8; off; off >>= 1) mx = fmaxf(mx, __shfl_xor(mx, off));
      float mn = fmaxf(m_r[r], mx);
      float sc = __expf(m_r[r] - mn);
      m_r[r] = mn;
      l_r[r] *= sc;
#pragma unroll
      for (int dt = 0; dt < 4; dt++) o_acc[dt][r] *= sc;
      float ts = 0.f;
#pragma unroll
      for (int nt = 0; nt < 4; nt++) {
        float p = __expf(s_acc[nt][r] - mn);
        s_acc[nt][r] = p;
        ts += p;
      }
#pragma unroll
      for (int off = 8; off; off >>= 1) ts += __shfl_xor(ts, off);
      l_r[r] += ts;
    }

    // P: C-layout -> per-wave LDS -> A-layout frags
#pragma unroll
    for (int nt = 0; nt < 4; nt++)
#pragma unroll
      for (int r = 0; r < 4; r++)
        Pl[w][g * 4 + r][nt * 16 + l16] = s_acc[nt][r];

#pragma unroll
    for (int ks = 0; ks < 2; ks++) {
      const float* pp = &Pl[w][l16][ks * 32 + g * 8];
      float4 p0 = *(const float4*)pp;
      float4 p1 = *(const float4*)(pp + 4);
      short8_t pf;
      pf[0] = (short)f2bf(p0.x); pf[1] = (short)f2bf(p0.y);
      pf[2] = (short)f2bf(p0.z); pf[3] = (short)f2bf(p0.w);
      pf[4] = (short)f2bf(p1.x); pf[5] = (short)f2bf(p1.y);
      pf[6] = (short)f2bf(p1.z); pf[7] = (short)f2bf(p1.w);
#pragma unroll
      for (int dt = 0; dt < 4; dt++) {
        const unsigned short* vp = &Vt[dt * 16 + l16][ks * 32 + g * 8];
        short4_t v0 = *(const short4_t*)vp;
        short4_t v1 = *(const short4_t*)(vp + 4);
        short8_t vf;
#pragma unroll
        for (int e = 0; e < 4; e++) { vf[e] = v0[e]; vf[4 + e] = v1[e]; }
        o_acc[dt] = __builtin_amdgcn_mfma_f32_16x16x32_bf16(pf, vf, o_acc[dt], 0, 0, 0);
      }
    }
  }

  // normalize + write: O row=g*4+r, col=l16+16*dt
  float* obase = o + (size_t)(b * Sc + q0) * Ec + h * 64;
#pragma unroll
  for (int r = 0; r < 4; r++) {
    float inv = 1.f / l_r[r];
    int qrow = g * 4 + r;
#pragma unroll
    for (int dt = 0; dt < 4; dt++)
      obase[(size_t)qrow * Ec + dt * 16 + l16] = o_acc[dt][r] * inv;
  }
}

// ============ LN over rows of E=768. MODE 0: plain out. MODE 1: +res, transposed out ============
template<int MODE>
__global__ __launch_bounds__(256) void k_lnrow(const float* __restrict__ in,
    const float* __restrict__ res, const float* __restrict__ g,
    const float* __restrict__ bt, float* __restrict__ out) {
  int row = blockIdx.x;
  int tid = threadIdx.x;
  __shared__ float buf[Ec];
  __shared__ float rsum[4], rss[4];
  float sum = 0.f, ss = 0.f;
  for (int i = tid; i < Ec; i += 256) {
    float v = in[(size_t)row * Ec + i];
    if (MODE == 1) v += res[(size_t)row * Ec + i];
    buf[i] = v; sum += v; ss += v * v;
  }
#pragma unroll
  for (int off = 32; off > 0; off >>= 1) {
    sum += __shfl_xor(sum, off); ss += __shfl_xor(ss, off);
  }
  if ((tid & 63) == 0) { rsum[tid >> 6] = sum; rss[tid >> 6] = ss; }
  __syncthreads();
  sum = rsum[0] + rsum[1] + rsum[2] + rsum[3];
  ss = rss[0] + rss[1] + rss[2] + rss[3];
  float mean = sum / Ec;
  float rstd = rsqrtf(ss / Ec - mean * mean + 1e-5f);
  if (MODE == 0) {
    for (int i = tid; i < Ec; i += 256)
      out[(size_t)row * Ec + i] = (buf[i] - mean) * rstd * g[i] + bt[i];
  } else {
    int b = row >> 10, s = row & 1023;
    for (int i = tid; i < Ec; i += 256)
      out[((size_t)b * Ec + i) * Sc + s] = (buf[i] - mean) * rstd * g[i] + bt[i];
  }
}

// ============ per-node attention coefficients a_s, a_d ============
__global__ __launch_bounds__(256) void k_asd(const float* __restrict__ hN,
    const float* __restrict__ att_src, const float* __restrict__ att_dst,
    float* __restrict__ a_s, float* __restrict__ a_d) {
  int n = blockIdx.x * 4 + (threadIdx.x >> 6);
  int lane = threadIdx.x & 63;
  const float* hrow = hN + (size_t)n * Ec;
#pragma unroll
  for (int h = 0; h < GHEAD; h++) {
    float ps = 0.f, pd = 0.f;
    for (int d = lane; d < DGAT; d += 64) {
      float v = hrow[h * DGAT + d];
      ps += v * att_src[h * DGAT + d];
      pd += v * att_dst[h * DGAT + d];
    }
#pragma unroll
    for (int off = 32; off > 0; off >>= 1) {
      ps += __shfl_xor(ps, off); pd += __shfl_xor(pd, off);
    }
    if (lane == 0) { a_s[n * GHEAD + h] = ps; a_d[n * GHEAD + h] = pd; }
  }
}

// ============ GAT stencil: softmax over (valid 8-nbrs + self), aggregate, elu, residual ============
__global__ __launch_bounds__(256) void k_gat(const float* __restrict__ hN,
    const float* __restrict__ a_s, const float* __restrict__ a_d,
    const float* __restrict__ x_attn, const float* __restrict__ gat_b,
    float* __restrict__ x_after) {
  int n = blockIdx.x;
  int b = n >> 10, s = n & 1023, r = s >> 5, c = s & 31;
  __shared__ int nbr[9];
  __shared__ float alpha[GHEAD][9];
  int tid = threadIdx.x;
  if (tid < 9) {
    int dr = tid / 3 - 1, dc = tid % 3 - 1;
    int rr = r + dr, cc = c + dc;
    int ok = (rr >= 0 && rr < 32 && cc >= 0 && cc < 32);
    // reference quirk: anti-diagonal edges exist only when upper endpoint's column <= W-2
    if (dr == -1 && dc == 1 && cc == 31) ok = 0;   // upper endpoint (rr,cc)
    if (dr == 1 && dc == -1 && c == 31) ok = 0;    // upper endpoint (r,c)
    nbr[tid] = ok ? ((b << 10) + (rr << 5) + cc) : -1;
  }
  __syncthreads();
  if (tid < GHEAD) {
    int h = tid;
    float ad = a_d[n * GHEAD + h];
    float ev[9]; float m = -1e30f;
#pragma unroll
    for (int j = 0; j < 9; j++) {
      if (nbr[j] >= 0) {
        float e = a_s[nbr[j] * GHEAD + h] + ad;
        e = e > 0.f ? e : 0.2f * e;   // leaky_relu 0.2
        ev[j] = e; m = fmaxf(m, e);
      } else ev[j] = -1e30f;
    }
    float den = 0.f;
#pragma unroll
    for (int j = 0; j < 9; j++) {
      float x = (nbr[j] >= 0) ? expf(ev[j] - m) : 0.f;
      ev[j] = x; den += x;
    }
    float inv = 1.f / den;
#pragma unroll
    for (int j = 0; j < 9; j++) alpha[h][j] = ev[j] * inv;
  }
  __syncthreads();
  for (int e = tid; e < Ec; e += 256) {
    int h = e / DGAT;
    float acc = 0.f;
#pragma unroll
    for (int j = 0; j < 9; j++) {
      int nj = nbr[j];
      if (nj >= 0) acc += alpha[h][j] * hN[(size_t)nj * Ec + e];
    }
    float v = acc + gat_b[e];
    v = v > 0.f ? v : expf(v) - 1.f;   // elu
    x_after[(size_t)n * Ec + e] = x_attn[(size_t)n * Ec + e] + v;
  }
}

extern "C" void kernel_launch(void* const* d_in, const int* in_sizes, int n_in,
                              void* d_out, int out_size, void* d_ws, size_t ws_size,
                              hipStream_t stream) {
  (void)in_sizes; (void)n_in; (void)out_size; (void)ws_size;
  const float* x      = (const float*)d_in[0];
  const float* ln1_g  = (const float*)d_in[1];
  const float* ln1_b  = (const float*)d_in[2];
  const float* proj_w = (const float*)d_in[3];
  const float* proj_b = (const float*)d_in[4];
  const float* wqkv   = (const float*)d_in[5];
  const float* bqkv   = (const float*)d_in[6];
  const float* wo     = (const float*)d_in[7];
  const float* bo     = (const float*)d_in[8];
  const float* ln2_g  = (const float*)d_in[9];
  const float* ln2_b  = (const float*)d_in[10];
  const float* gp_w   = (const float*)d_in[11];
  const float* gp_b   = (const float*)d_in[12];
  const float* gat_w  = (const float*)d_in[13];
  const float* att_src= (const float*)d_in[14];
  const float* att_dst= (const float*)d_in[15];
  const float* gat_b  = (const float*)d_in[16];
  const float* ln3_g  = (const float*)d_in[17];
  const float* ln3_b  = (const float*)d_in[18];
  const float* mlp_w1 = (const float*)d_in[19];
  const float* mlp_b1 = (const float*)d_in[20];
  const float* mlp_w2 = (const float*)d_in[21];
  const float* mlp_b2 = (const float*)d_in[22];
  const float* fn_g   = (const float*)d_in[23];
  const float* fn_b   = (const float*)d_in[24];
  float* out = (float*)d_out;

  float* ws = (float*)d_ws;
  float* n1t    = ws;                   // [2048][4096]  (reused later as qkv)
  float* qkv    = ws;                   // [4096][2304]
  float* v_in   = ws + 9437184;         // [4096][768]   (later n3)
  float* o_buf  = ws + 12582912;        // [4096][768]   (later x_after)
  float* x_attn = ws + 15728640;        // [4096][768]
  float* n2     = ws + 18874368;        // [4096][768]   (later mlp hidden)
  float* gbuf   = ws + 22020096;        // [4096][768]   (later mlp out)
  float* hN     = ws + 25165824;        // [4096][768]
  float* a_s    = ws + 28311552;        // [4096][4]
  float* a_d    = a_s + 16384;          // [4096][4]

  // 1) LN over C + transpose-store
  k_ln1<<<256, 256, 0, stream>>>(x, ln1_g, ln1_b, n1t);
  // 2) v_in = n1 @ proj_w + proj_b   (A in [K][M] layout)
  gemm_f32<1, 1><<<dim3(Ec / 128, Ntok / 128), 256, 0, stream>>>(
      n1t, proj_w, proj_b, nullptr, v_in, Ntok, Ec, Cc);
  // 3) qkv = v_in @ wqkv + bqkv  (writes over n1t region)
  gemm_f32<0, 1><<<dim3(E3 / 128, Ntok / 128), 256, 0, stream>>>(
      v_in, wqkv, bqkv, nullptr, qkv, Ntok, E3, Ec);
  // 4) attention (MFMA bf16 flash)
  k_attn_mfma<<<dim3(16, NHEAD, Bc), 256, 0, stream>>>(qkv, o_buf);
  // 5) x_attn = v_in + o @ wo + bo
  gemm_f32<0, 2><<<dim3(Ec / 128, Ntok / 128), 256, 0, stream>>>(
      o_buf, wo, bo, v_in, x_attn, Ntok, Ec, Ec);
  // 6) n2 = LN(x_attn)
  k_lnrow<0><<<Ntok, 256, 0, stream>>>(x_attn, nullptr, ln2_g, ln2_b, n2);
  // 7) g = n2 @ gp_w + gp_b
  gemm_f32<0, 1><<<dim3(Ec / 128, Ntok / 128), 256, 0, stream>>>(
      n2, gp_w, gp_b, nullptr, gbuf, Ntok, Ec, Ec);
  // 8) hN = g @ gat_w  (no bias)
  gemm_f32<0, 0><<<dim3(Ec / 128, Ntok / 128), 256, 0, stream>>>(
      gbuf, gat_w, nullptr, nullptr, hN, Ntok, Ec, Ec);
  // 9) a_s, a_d
  k_asd<<<Ntok / 4, 256, 0, stream>>>(hN, att_src, att_dst, a_s, a_d);
  // 10) GAT aggregate + elu + residual -> x_after (reuses o_buf)
  k_gat<<<Ntok, 256, 0, stream>>>(hN, a_s, a_d, x_attn, gat_b, o_buf);
  // 11) n3 = LN(x_after)  (reuses v_in)
  k_lnrow<0><<<Ntok, 256, 0, stream>>>(o_buf, nullptr, ln3_g, ln3_b, v_in);
  // 12) h1 = gelu(n3 @ mlp_w1 + mlp_b1)  (reuses n2)
  gemm_f32<0, 3><<<dim3(Ec / 128, Ntok / 128), 256, 0, stream>>>(
      v_in, mlp_w1, mlp_b1, nullptr, n2, Ntok, Ec, Ec);
  // 13) mlp = h1 @ mlp_w2 + mlp_b2  (reuses gbuf)
  gemm_f32<0, 1><<<dim3(Ec / 128, Ntok / 128), 256, 0, stream>>>(
      n2, mlp_w2, mlp_b2, nullptr, gbuf, Ntok, Ec, Ec);
  // 14) out = LN(n3 + mlp), transposed to [B,E,H,W]
  k_lnrow<1><<<Ntok, 256, 0, stream>>>(v_in, gbuf, fn_g, fn_b, out);
}

// Round 3
// 358.660 us; speedup vs baseline: 6.4977x; 3.3570x over previous
//
#include <hip/hip_runtime.h>

// ---- problem constants ----
constexpr int Bc = 4;
constexpr int Cc = 2048;
constexpr int Sc = 1024;     // H*W = 32*32
constexpr int Ntok = 4096;   // B*S
constexpr int Ec = 768;
constexpr int E3 = 2304;
constexpr int NHEAD = 12;
constexpr int GHEAD = 4;
constexpr int DGAT = 192;

typedef __attribute__((ext_vector_type(8))) short short8_t;   // bf16x8 MFMA frag
typedef __attribute__((ext_vector_type(8))) unsigned short u16x8;
typedef __attribute__((ext_vector_type(4))) float f32x4;

__device__ inline unsigned short f2bf(float f) {
  unsigned int u = __builtin_bit_cast(unsigned int, f);
  u += 0x7FFFu + ((u >> 16) & 1u);     // RNE
  return (unsigned short)(u >> 16);
}

// ============ fused weight transpose+bf16: [K][N] f32 -> [N][K] bf16, 7 weights ============
struct WtArgs {
  const float* src[7];
  unsigned short* dst[7];
  int K[7], N[7];
  int off[8];
};
__global__ __launch_bounds__(256) void k_wt(WtArgs a) {
  __shared__ float t[32][33];
  int bid = blockIdx.x;
  int w = 0;
  while (w < 6 && bid >= a.off[w + 1]) ++w;
  int local = bid - a.off[w];
  int K = a.K[w], N = a.N[w];
  int ntn = N >> 5;
  int tk = local / ntn, tn = local - tk * ntn;
  int k0 = tk * 32, n0 = tn * 32;
  int tx = threadIdx.x & 31, ty = threadIdx.x >> 5;
  const float* src = a.src[w];
#pragma unroll
  for (int i = 0; i < 4; i++)
    t[ty + i * 8][tx] = src[(size_t)(k0 + ty + i * 8) * N + n0 + tx];
  __syncthreads();
  unsigned short* dst = a.dst[w];
#pragma unroll
  for (int i = 0; i < 4; i++)
    dst[(size_t)(n0 + ty + i * 8) * K + k0 + tx] = f2bf(t[tx][ty + i * 8]);
}

// ============ LN1 over C=2048, writes bf16 n1[M][C] (row-major, GEMM-A-ready) ============
__global__ __launch_bounds__(256) void k_ln1_bf(const float* __restrict__ x,
    const float* __restrict__ g, const float* __restrict__ bt,
    unsigned short* __restrict__ out) {
  int blk = blockIdx.x;          // 512 blocks: b(4) x 128 tiles of 8 s
  int b = blk >> 7;
  int s0 = (blk & 127) << 3;
  int sl = threadIdx.x & 7;
  int cl = threadIdx.x >> 3;     // 0..31
  int s = s0 + sl;
  const float* xb = x + (size_t)b * Cc * Sc + s;
  float sum = 0.f, ss = 0.f;
  for (int c = cl; c < Cc; c += 32) {
    float v = xb[(size_t)c * Sc];
    sum += v; ss += v * v;
  }
  __shared__ float rs0[32][9], rs1[32][9];
  __shared__ float mean_s[8], rstd_s[8];
  rs0[cl][sl] = sum; rs1[cl][sl] = ss;
  __syncthreads();
  if (threadIdx.x < 8) {
    float a = 0.f, q = 0.f;
    for (int i = 0; i < 32; i++) { a += rs0[i][threadIdx.x]; q += rs1[i][threadIdx.x]; }
    float mean = a / Cc;
    float var = q / Cc - mean * mean;
    mean_s[threadIdx.x] = mean; rstd_s[threadIdx.x] = rsqrtf(var + 1e-5f);
  }
  __syncthreads();
  __shared__ unsigned short T[8][2056];   // pad -> row stride 4112B, banks spread
  float mean = mean_s[sl], rstd = rstd_s[sl];
  for (int c = cl; c < Cc; c += 32) {
    float v = xb[(size_t)c * Sc];
    T[sl][c] = f2bf((v - mean) * rstd * g[c] + bt[c]);
  }
  __syncthreads();
  unsigned short* ob = out + ((size_t)(b * Sc) + s0) * Cc;
#pragma unroll
  for (int r = 0; r < 8; r++)
    *(u16x8*)&ob[(size_t)r * Cc + threadIdx.x * 8] = *(const u16x8*)&T[r][threadIdx.x * 8];
}

// ============ bf16 MFMA GEMM: C[M][N] = A[M][K] @ Bt[N][K]^T ============
// 128x128 tile, BK=64, 256 thr = 4 waves (2x2), each wave 64x64 via 4x4 16x16 frags.
// EPI: 0 none, 1 +bias, 2 +bias+res, 3 +bias+gelu(exact). OUTM bit0: f32 out, bit1: bf16 out.
template<int EPI, int OUTM>
__global__ __launch_bounds__(256) void gemm_bf16(
    const unsigned short* __restrict__ A, const unsigned short* __restrict__ Bt,
    const float* __restrict__ bias, const float* __restrict__ res,
    float* __restrict__ Cf, unsigned short* __restrict__ Cb,
    int M, int N, int K) {
  __shared__ unsigned short As[128][72];   // pad 64->72: row 144B, 2-way-free b128 reads
  __shared__ unsigned short Bs[128][72];
  int tid = threadIdx.x;
  int w = tid >> 6, lane = tid & 63, g = lane >> 4, l16 = lane & 15;
  int wm = w >> 1, wn = w & 1;
  int m0 = blockIdx.y * 128, n0 = blockIdx.x * 128;
  f32x4 acc[4][4] = {};
  for (int k0 = 0; k0 < K; k0 += 64) {
    __syncthreads();
#pragma unroll
    for (int it = 0; it < 4; it++) {
      int idx = tid + it * 256;
      int r = idx >> 3, ch = idx & 7;
      *(u16x8*)&As[r][ch * 8] = *(const u16x8*)&A[(size_t)(m0 + r) * K + k0 + ch * 8];
      *(u16x8*)&Bs[r][ch * 8] = *(const u16x8*)&Bt[(size_t)(n0 + r) * K + k0 + ch * 8];
    }
    __syncthreads();
#pragma unroll
    for (int ks = 0; ks < 2; ks++) {
      short8_t af[4], bf[4];
#pragma unroll
      for (int i = 0; i < 4; i++) {
        af[i] = *(const short8_t*)&As[wm * 64 + i * 16 + l16][ks * 32 + g * 8];
        bf[i] = *(const short8_t*)&Bs[wn * 64 + i * 16 + l16][ks * 32 + g * 8];
      }
#pragma unroll
      for (int mi = 0; mi < 4; mi++)
#pragma unroll
        for (int ni = 0; ni < 4; ni++)
          acc[mi][ni] = __builtin_amdgcn_mfma_f32_16x16x32_bf16(af[mi], bf[ni], acc[mi][ni], 0, 0, 0);
    }
  }
#pragma unroll
  for (int mi = 0; mi < 4; mi++) {
#pragma unroll
    for (int ni = 0; ni < 4; ni++) {
      int n = n0 + wn * 64 + ni * 16 + l16;
      float bv = 0.f;
      if (EPI != 0) bv = bias[n];
#pragma unroll
      for (int r = 0; r < 4; r++) {
        int m = m0 + wm * 64 + mi * 16 + g * 4 + r;
        float c = acc[mi][ni][r] + bv;
        if (EPI == 2) c += res[(size_t)m * N + n];
        if (EPI == 3) c = 0.5f * c * (1.f + erff(c * 0.70710678118f));
        if (OUTM & 1) Cf[(size_t)m * N + n] = c;
        if (OUTM & 2) Cb[(size_t)m * N + n] = f2bf(c);
      }
    }
  }
}

// ============ MHSA via MFMA bf16 (bf16 qkv in, bf16 o out), flash-style ============
__global__ __launch_bounds__(256) void k_attn_mfma(const unsigned short* __restrict__ qkv,
    unsigned short* __restrict__ o) {
  __shared__ unsigned short Ks[64][72];
  __shared__ unsigned short Vt[64][72];
  __shared__ float Pl[4][16][68];
  int qt = blockIdx.x, h = blockIdx.y, b = blockIdx.z;
  int tid = threadIdx.x;
  int w = tid >> 6, lane = tid & 63;
  int g = lane >> 4, l16 = lane & 15;
  const unsigned short* base  = qkv + (size_t)b * Sc * E3;
  const unsigned short* kbase = base + Ec + h * 64;
  const unsigned short* vbase = base + 2 * Ec + h * 64;
  int q0 = qt * 64 + w * 16;

  short8_t qf[2];
#pragma unroll
  for (int ks = 0; ks < 2; ks++)
    qf[ks] = *(const short8_t*)&base[(size_t)(q0 + l16) * E3 + h * 64 + ks * 32 + g * 8];

  f32x4 o_acc[4] = {};
  float m_r[4] = {-1e30f, -1e30f, -1e30f, -1e30f};
  float l_r[4] = {};

  for (int kt = 0; kt < 16; kt++) {
    __syncthreads();
#pragma unroll
    for (int it = 0; it < 2; it++) {
      int idx = tid + it * 256;
      int r = idx >> 3, ch = idx & 7;
      *(u16x8*)&Ks[r][ch * 8] = *(const u16x8*)&kbase[(size_t)(kt * 64 + r) * E3 + ch * 8];
    }
#pragma unroll
    for (int it = 0; it < 8; it++) {
      int idx = tid + it * 256;
      int c = idx & 63, rp = idx >> 6;
      unsigned int pa = (unsigned int)vbase[(size_t)(kt * 64 + 2 * rp) * E3 + c]
                      | ((unsigned int)vbase[(size_t)(kt * 64 + 2 * rp + 1) * E3 + c] << 16);
      *(unsigned int*)&Vt[c][2 * rp] = pa;
    }
    __syncthreads();

    f32x4 s_acc[4] = {};
#pragma unroll
    for (int nt = 0; nt < 4; nt++) {
#pragma unroll
      for (int ks = 0; ks < 2; ks++) {
        short8_t kf = *(const short8_t*)&Ks[nt * 16 + l16][ks * 32 + g * 8];
        s_acc[nt] = __builtin_amdgcn_mfma_f32_16x16x32_bf16(qf[ks], kf, s_acc[nt], 0, 0, 0);
      }
    }
    // fold 1/sqrt(dh) here instead of scaling Q
#pragma unroll
    for (int nt = 0; nt < 4; nt++)
#pragma unroll
      for (int r = 0; r < 4; r++) s_acc[nt][r] *= 0.125f;

#pragma unroll
    for (int r = 0; r < 4; r++) {
      float mx = fmaxf(fmaxf(s_acc[0][r], s_acc[1][r]), fmaxf(s_acc[2][r], s_acc[3][r]));
#pragma unroll
      for (int off = 8; off; off >>= 1) mx = fmaxf(mx, __shfl_xor(mx, off));
      float mn = fmaxf(m_r[r], mx);
      float sc = __expf(m_r[r] - mn);
      m_r[r] = mn;
      l_r[r] *= sc;
#pragma unroll
      for (int dt = 0; dt < 4; dt++) o_acc[dt][r] *= sc;
      float ts = 0.f;
#pragma unroll
      for (int nt = 0; nt < 4; nt++) {
        float p = __expf(s_acc[nt][r] - mn);
        s_acc[nt][r] = p;
        ts += p;
      }
#pragma unroll
      for (int off = 8; off; off >>= 1) ts += __shfl_xor(ts, off);
      l_r[r] += ts;
    }

#pragma unroll
    for (int nt = 0; nt < 4; nt++)
#pragma unroll
      for (int r = 0; r < 4; r++)
        Pl[w][g * 4 + r][nt * 16 + l16] = s_acc[nt][r];

#pragma unroll
    for (int ks = 0; ks < 2; ks++) {
      const float* pp = &Pl[w][l16][ks * 32 + g * 8];
      float4 p0 = *(const float4*)pp;
      float4 p1 = *(const float4*)(pp + 4);
      short8_t pf;
      pf[0] = (short)f2bf(p0.x); pf[1] = (short)f2bf(p0.y);
      pf[2] = (short)f2bf(p0.z); pf[3] = (short)f2bf(p0.w);
      pf[4] = (short)f2bf(p1.x); pf[5] = (short)f2bf(p1.y);
      pf[6] = (short)f2bf(p1.z); pf[7] = (short)f2bf(p1.w);
#pragma unroll
      for (int dt = 0; dt < 4; dt++) {
        short8_t vf = *(const short8_t*)&Vt[dt * 16 + l16][ks * 32 + g * 8];
        o_acc[dt] = __builtin_amdgcn_mfma_f32_16x16x32_bf16(pf, vf, o_acc[dt], 0, 0, 0);
      }
    }
  }

  unsigned short* obase = o + (size_t)(b * Sc + q0) * Ec + h * 64;
#pragma unroll
  for (int r = 0; r < 4; r++) {
    float inv = 1.f / l_r[r];
    int qrow = g * 4 + r;
#pragma unroll
    for (int dt = 0; dt < 4; dt++)
      obase[(size_t)qrow * Ec + dt * 16 + l16] = f2bf(o_acc[dt][r] * inv);
  }
}

// ============ LN over rows of E=768 ============
// MODE 0: bf16 out only. MODE 2: f32 + bf16 out. MODE 1: in+res, f32 transposed out.
template<int MODE>
__global__ __launch_bounds__(256) void k_lnrow(const float* __restrict__ in,
    const float* __restrict__ res, const float* __restrict__ g,
    const float* __restrict__ bt, float* __restrict__ outf,
    unsigned short* __restrict__ outb) {
  int row = blockIdx.x;
  int tid = threadIdx.x;
  __shared__ float buf[Ec];
  __shared__ float rsum[4], rss[4];
  float sum = 0.f, ss = 0.f;
  for (int i = tid; i < Ec; i += 256) {
    float v = in[(size_t)row * Ec + i];
    if (MODE == 1) v += res[(size_t)row * Ec + i];
    buf[i] = v; sum += v; ss += v * v;
  }
#pragma unroll
  for (int off = 32; off > 0; off >>= 1) {
    sum += __shfl_xor(sum, off); ss += __shfl_xor(ss, off);
  }
  if ((tid & 63) == 0) { rsum[tid >> 6] = sum; rss[tid >> 6] = ss; }
  __syncthreads();
  sum = rsum[0] + rsum[1] + rsum[2] + rsum[3];
  ss = rss[0] + rss[1] + rss[2] + rss[3];
  float mean = sum / Ec;
  float rstd = rsqrtf(ss / Ec - mean * mean + 1e-5f);
  if (MODE == 1) {
    int b = row >> 10, s = row & 1023;
    for (int i = tid; i < Ec; i += 256)
      outf[((size_t)b * Ec + i) * Sc + s] = (buf[i] - mean) * rstd * g[i] + bt[i];
  } else {
    for (int i = tid; i < Ec; i += 256) {
      float v = (buf[i] - mean) * rstd * g[i] + bt[i];
      if (MODE == 2) outf[(size_t)row * Ec + i] = v;
      outb[(size_t)row * Ec + i] = f2bf(v);
    }
  }
}

// ============ per-node attention coefficients a_s, a_d ============
__global__ __launch_bounds__(256) void k_asd(const float* __restrict__ hN,
    const float* __restrict__ att_src, const float* __restrict__ att_dst,
    float* __restrict__ a_s, float* __restrict__ a_d) {
  int n = blockIdx.x * 4 + (threadIdx.x >> 6);
  int lane = threadIdx.x & 63;
  const float* hrow = hN + (size_t)n * Ec;
#pragma unroll
  for (int h = 0; h < GHEAD; h++) {
    float ps = 0.f, pd = 0.f;
    for (int d = lane; d < DGAT; d += 64) {
      float v = hrow[h * DGAT + d];
      ps += v * att_src[h * DGAT + d];
      pd += v * att_dst[h * DGAT + d];
    }
#pragma unroll
    for (int off = 32; off > 0; off >>= 1) {
      ps += __shfl_xor(ps, off); pd += __shfl_xor(pd, off);
    }
    if (lane == 0) { a_s[n * GHEAD + h] = ps; a_d[n * GHEAD + h] = pd; }
  }
}

// ============ GAT stencil ============
__global__ __launch_bounds__(256) void k_gat(const float* __restrict__ hN,
    const float* __restrict__ a_s, const float* __restrict__ a_d,
    const float* __restrict__ x_attn, const float* __restrict__ gat_b,
    float* __restrict__ x_after) {
  int n = blockIdx.x;
  int b = n >> 10, s = n & 1023, r = s >> 5, c = s & 31;
  __shared__ int nbr[9];
  __shared__ float alpha[GHEAD][9];
  int tid = threadIdx.x;
  if (tid < 9) {
    int dr = tid / 3 - 1, dc = tid % 3 - 1;
    int rr = r + dr, cc = c + dc;
    int ok = (rr >= 0 && rr < 32 && cc >= 0 && cc < 32);
    // reference quirk: anti-diagonal edges exist only when upper endpoint's column <= W-2
    if (dr == -1 && dc == 1 && cc == 31) ok = 0;
    if (dr == 1 && dc == -1 && c == 31) ok = 0;
    nbr[tid] = ok ? ((b << 10) + (rr << 5) + cc) : -1;
  }
  __syncthreads();
  if (tid < GHEAD) {
    int h = tid;
    float ad = a_d[n * GHEAD + h];
    float ev[9]; float m = -1e30f;
#pragma unroll
    for (int j = 0; j < 9; j++) {
      if (nbr[j] >= 0) {
        float e = a_s[nbr[j] * GHEAD + h] + ad;
        e = e > 0.f ? e : 0.2f * e;
        ev[j] = e; m = fmaxf(m, e);
      } else ev[j] = -1e30f;
    }
    float den = 0.f;
#pragma unroll
    for (int j = 0; j < 9; j++) {
      float x = (nbr[j] >= 0) ? expf(ev[j] - m) : 0.f;
      ev[j] = x; den += x;
    }
    float inv = 1.f / den;
#pragma unroll
    for (int j = 0; j < 9; j++) alpha[h][j] = ev[j] * inv;
  }
  __syncthreads();
  for (int e = tid; e < Ec; e += 256) {
    int h = e / DGAT;
    float acc = 0.f;
#pragma unroll
    for (int j = 0; j < 9; j++) {
      int nj = nbr[j];
      if (nj >= 0) acc += alpha[h][j] * hN[(size_t)nj * Ec + e];
    }
    float v = acc + gat_b[e];
    v = v > 0.f ? v : expf(v) - 1.f;
    x_after[(size_t)n * Ec + e] = x_attn[(size_t)n * Ec + e] + v;
  }
}

extern "C" void kernel_launch(void* const* d_in, const int* in_sizes, int n_in,
                              void* d_out, int out_size, void* d_ws, size_t ws_size,
                              hipStream_t stream) {
  (void)in_sizes; (void)n_in; (void)out_size; (void)ws_size;
  const float* x      = (const float*)d_in[0];
  const float* ln1_g  = (const float*)d_in[1];
  const float* ln1_b  = (const float*)d_in[2];
  const float* proj_w = (const float*)d_in[3];
  const float* proj_b = (const float*)d_in[4];
  const float* wqkv   = (const float*)d_in[5];
  const float* bqkv   = (const float*)d_in[6];
  const float* wo     = (const float*)d_in[7];
  const float* bo     = (const float*)d_in[8];
  const float* ln2_g  = (const float*)d_in[9];
  const float* ln2_b  = (const float*)d_in[10];
  const float* gp_w   = (const float*)d_in[11];
  const float* gp_b   = (const float*)d_in[12];
  const float* gat_w  = (const float*)d_in[13];
  const float* att_src= (const float*)d_in[14];
  const float* att_dst= (const float*)d_in[15];
  const float* gat_b  = (const float*)d_in[16];
  const float* ln3_g  = (const float*)d_in[17];
  const float* ln3_b  = (const float*)d_in[18];
  const float* mlp_w1 = (const float*)d_in[19];
  const float* mlp_b1 = (const float*)d_in[20];
  const float* mlp_w2 = (const float*)d_in[21];
  const float* mlp_b2 = (const float*)d_in[22];
  const float* fn_g   = (const float*)d_in[23];
  const float* fn_b   = (const float*)d_in[24];
  float* out = (float*)d_out;

  // ---- workspace layout (byte offsets, all deterministic) ----
  char* p = (char*)d_ws;
  auto alloc = [&](size_t bytes) { char* q = p; p += (bytes + 255) & ~(size_t)255; return q; };
  // region shared by n1_bf (dead after proj GEMM) and qkv_bf (written after)
  char* regA      = alloc((size_t)Ntok * E3 * 2);            // 18.9MB
  unsigned short* n1_bf  = (unsigned short*)regA;            // [4096][2048] bf16
  unsigned short* qkv_bf = (unsigned short*)regA;            // [4096][2304] bf16
  unsigned short* proj_wt = (unsigned short*)alloc((size_t)Ec * Cc * 2);   // [768][2048]
  unsigned short* wqkv_t  = (unsigned short*)alloc((size_t)E3 * Ec * 2);   // [2304][768]
  unsigned short* wo_t    = (unsigned short*)alloc((size_t)Ec * Ec * 2);
  unsigned short* gp_t    = (unsigned short*)alloc((size_t)Ec * Ec * 2);
  unsigned short* gat_t   = (unsigned short*)alloc((size_t)Ec * Ec * 2);
  unsigned short* m1_t    = (unsigned short*)alloc((size_t)Ec * Ec * 2);
  unsigned short* m2_t    = (unsigned short*)alloc((size_t)Ec * Ec * 2);
  float* v_in   = (float*)alloc((size_t)Ntok * Ec * 4);
  unsigned short* v_in_bf = (unsigned short*)alloc((size_t)Ntok * Ec * 2);
  unsigned short* regE    = (unsigned short*)alloc((size_t)Ntok * Ec * 2); // o_bf -> h1_bf
  float* regF   = (float*)alloc((size_t)Ntok * Ec * 4);      // x_attn -> n3 f32
  unsigned short* regG    = (unsigned short*)alloc((size_t)Ntok * Ec * 2); // n2_bf -> n3_bf
  unsigned short* g_bf    = (unsigned short*)alloc((size_t)Ntok * Ec * 2);
  float* hN     = (float*)alloc((size_t)Ntok * Ec * 4);
  float* regJ   = (float*)alloc((size_t)Ntok * Ec * 4);      // x_after -> mlp_out
  float* a_s    = (float*)alloc((size_t)Ntok * GHEAD * 4);
  float* a_d    = (float*)alloc((size_t)Ntok * GHEAD * 4);

  unsigned short* o_bf   = regE;
  unsigned short* h1_bf  = regE;
  float* x_attn = regF;
  float* n3_f   = regF;
  unsigned short* n2_bf  = regG;
  unsigned short* n3_bf  = regG;
  float* x_after = regJ;
  float* mlp_out = regJ;

  // 0) weights -> transposed bf16 (every call; deterministic)
  WtArgs wa;
  wa.src[0] = proj_w; wa.dst[0] = proj_wt; wa.K[0] = Cc; wa.N[0] = Ec;
  wa.src[1] = wqkv;   wa.dst[1] = wqkv_t;  wa.K[1] = Ec; wa.N[1] = E3;
  wa.src[2] = wo;     wa.dst[2] = wo_t;    wa.K[2] = Ec; wa.N[2] = Ec;
  wa.src[3] = gp_w;   wa.dst[3] = gp_t;    wa.K[3] = Ec; wa.N[3] = Ec;
  wa.src[4] = gat_w;  wa.dst[4] = gat_t;   wa.K[4] = Ec; wa.N[4] = Ec;
  wa.src[5] = mlp_w1; wa.dst[5] = m1_t;    wa.K[5] = Ec; wa.N[5] = Ec;
  wa.src[6] = mlp_w2; wa.dst[6] = m2_t;    wa.K[6] = Ec; wa.N[6] = Ec;
  int cum = 0;
  for (int i = 0; i < 7; i++) { wa.off[i] = cum; cum += (wa.K[i] >> 5) * (wa.N[i] >> 5); }
  wa.off[7] = cum;
  k_wt<<<cum, 256, 0, stream>>>(wa);

  // 1) LN1 -> bf16 [M][C]
  k_ln1_bf<<<512, 256, 0, stream>>>(x, ln1_g, ln1_b, n1_bf);
  // 2) v_in = n1 @ proj_w + proj_b  (f32 + bf16 out)
  gemm_bf16<1, 3><<<dim3(Ec / 128, Ntok / 128), 256, 0, stream>>>(
      n1_bf, proj_wt, proj_b, nullptr, v_in, v_in_bf, Ntok, Ec, Cc);
  // 3) qkv = v_in @ wqkv + bqkv  (bf16 out; overwrites n1_bf region)
  gemm_bf16<1, 2><<<dim3(E3 / 128, Ntok / 128), 256, 0, stream>>>(
      v_in_bf, wqkv_t, bqkv, nullptr, nullptr, qkv_bf, Ntok, E3, Ec);
  // 4) attention (bf16 in/out)
  k_attn_mfma<<<dim3(16, NHEAD, Bc), 256, 0, stream>>>(qkv_bf, o_bf);
  // 5) x_attn = v_in + o @ wo + bo  (f32)
  gemm_bf16<2, 1><<<dim3(Ec / 128, Ntok / 128), 256, 0, stream>>>(
      o_bf, wo_t, bo, v_in, x_attn, nullptr, Ntok, Ec, Ec);
  // 6) n2 = LN(x_attn) -> bf16
  k_lnrow<0><<<Ntok, 256, 0, stream>>>(x_attn, nullptr, ln2_g, ln2_b, nullptr, n2_bf);
  // 7) g = n2 @ gp_w + gp_b -> bf16
  gemm_bf16<1, 2><<<dim3(Ec / 128, Ntok / 128), 256, 0, stream>>>(
      n2_bf, gp_t, gp_b, nullptr, nullptr, g_bf, Ntok, Ec, Ec);
  // 8) hN = g @ gat_w -> f32
  gemm_bf16<0, 1><<<dim3(Ec / 128, Ntok / 128), 256, 0, stream>>>(
      g_bf, gat_t, nullptr, nullptr, hN, nullptr, Ntok, Ec, Ec);
  // 9) a_s, a_d
  k_asd<<<Ntok / 4, 256, 0, stream>>>(hN, att_src, att_dst, a_s, a_d);
  // 10) GAT aggregate + elu + residual -> x_after
  k_gat<<<Ntok, 256, 0, stream>>>(hN, a_s, a_d, x_attn, gat_b, x_after);
  // 11) n3 = LN(x_after) -> f32 + bf16
  k_lnrow<2><<<Ntok, 256, 0, stream>>>(x_after, nullptr, ln3_g, ln3_b, n3_f, n3_bf);
  // 12) h1 = gelu(n3 @ mlp_w1 + mlp_b1) -> bf16
  gemm_bf16<3, 2><<<dim3(Ec / 128, Ntok / 128), 256, 0, stream>>>(
      n3_bf, m1_t, mlp_b1, nullptr, nullptr, h1_bf, Ntok, Ec, Ec);
  // 13) mlp = h1 @ mlp_w2 + mlp_b2 -> f32
  gemm_bf16<1, 1><<<dim3(Ec / 128, Ntok / 128), 256, 0, stream>>>(
      h1_bf, m2_t, mlp_b2, nullptr, mlp_out, nullptr, Ntok, Ec, Ec);
  // 14) out = LN(n3 + mlp), transposed to [B,E,H,W]
  k_lnrow<1><<<Ntok, 256, 0, stream>>>(n3_f, mlp_out, fn_g, fn_b, out, nullptr);
}

// Round 4
// 348.577 us; speedup vs baseline: 6.6857x; 1.0289x over previous
//
#include <hip/hip_runtime.h>

// ---- problem constants ----
constexpr int Bc = 4;
constexpr int Cc = 2048;
constexpr int Sc = 1024;     // H*W = 32*32
constexpr int Ntok = 4096;   // B*S
constexpr int Ec = 768;
constexpr int E3 = 2304;
constexpr int NHEAD = 12;
constexpr int GHEAD = 4;
constexpr int DGAT = 192;

typedef __attribute__((ext_vector_type(8))) short short8_t;   // bf16x8 MFMA frag
typedef __attribute__((ext_vector_type(4))) short short4_t;
typedef __attribute__((ext_vector_type(8))) unsigned short u16x8;
typedef __attribute__((ext_vector_type(4))) float f32x4;

// single-instruction bf16 convert (RNE), replaces 5-op software round
__device__ inline unsigned short f2bf_hw(float f) {
  unsigned int r;
  asm("v_cvt_pk_bf16_f32 %0, %1, %1" : "=v"(r) : "v"(f));
  return (unsigned short)r;
}
__device__ inline float bf2f(unsigned short h) {
  unsigned int u = ((unsigned int)h) << 16;
  return __builtin_bit_cast(float, u);
}

// ============ fused weight transpose+bf16: [K][N] f32 -> [N][K] bf16, 7 weights ============
struct WtArgs {
  const float* src[7];
  unsigned short* dst[7];
  int K[7], N[7];
  int off[8];
};
__global__ __launch_bounds__(256) void k_wt(WtArgs a) {
  __shared__ float t[32][33];
  int bid = blockIdx.x;
  int w = 0;
  while (w < 6 && bid >= a.off[w + 1]) ++w;
  int local = bid - a.off[w];
  int K = a.K[w], N = a.N[w];
  int ntn = N >> 5;
  int tk = local / ntn, tn = local - tk * ntn;
  int k0 = tk * 32, n0 = tn * 32;
  int tx = threadIdx.x & 31, ty = threadIdx.x >> 5;
  const float* src = a.src[w];
#pragma unroll
  for (int i = 0; i < 4; i++)
    t[ty + i * 8][tx] = src[(size_t)(k0 + ty + i * 8) * N + n0 + tx];
  __syncthreads();
  unsigned short* dst = a.dst[w];
#pragma unroll
  for (int i = 0; i < 4; i++)
    dst[(size_t)(n0 + ty + i * 8) * K + k0 + tx] = f2bf_hw(t[tx][ty + i * 8]);
}

// ============ LN1 over C=2048, writes bf16 n1[M][C]; 16-wide s for full-line fetches ============
__global__ __launch_bounds__(256) void k_ln1_bf(const float* __restrict__ x,
    const float* __restrict__ g, const float* __restrict__ bt,
    unsigned short* __restrict__ out) {
  int blk = blockIdx.x;          // 256 blocks: b(4) x 64 tiles of 16 s
  int b = blk >> 6;
  int s0 = (blk & 63) << 4;
  int sl = threadIdx.x & 15;     // s lane (consecutive -> 64B lines)
  int cl = threadIdx.x >> 4;     // 0..15
  int s = s0 + sl;
  const float* xb = x + (size_t)b * Cc * Sc + s;
  float sum = 0.f, ss = 0.f;
  for (int c = cl; c < Cc; c += 16) {
    float v = xb[(size_t)c * Sc];
    sum += v; ss += v * v;
  }
  __shared__ float rs0[16][17], rs1[16][17];
  __shared__ float mean_s[16], rstd_s[16];
  rs0[cl][sl] = sum; rs1[cl][sl] = ss;
  __syncthreads();
  if (cl == 0) {
    float a = 0.f, q = 0.f;
    for (int i = 0; i < 16; i++) { a += rs0[i][sl]; q += rs1[i][sl]; }
    float mean = a / Cc;
    float var = q / Cc - mean * mean;
    mean_s[sl] = mean; rstd_s[sl] = rsqrtf(var + 1e-5f);
  }
  __syncthreads();
  float mean = mean_s[sl], rstd = rstd_s[sl];
  __shared__ unsigned short Tc[16][136];   // 128 c chunk + pad
  int rl = threadIdx.x >> 4, el = threadIdx.x & 15;
  unsigned short* ob = out + ((size_t)(b * Sc) + s0) * Cc;
  for (int ch = 0; ch < 16; ch++) {
    int cb = ch * 128;
#pragma unroll
    for (int t = 0; t < 8; t++) {
      int c = cb + cl + t * 16;
      float v = xb[(size_t)c * Sc];
      Tc[sl][cl + t * 16] = f2bf_hw((v - mean) * rstd * g[c] + bt[c]);
    }
    __syncthreads();
    *(u16x8*)&ob[(size_t)rl * Cc + cb + el * 8] = *(const u16x8*)&Tc[rl][el * 8];
    __syncthreads();
  }
}

// ============ bf16 MFMA GEMM: C[M][N] = A[M][K] @ Bt[N][K]^T ============
template<int EPI, int OUTM>
__global__ __launch_bounds__(256) void gemm_bf16(
    const unsigned short* __restrict__ A, const unsigned short* __restrict__ Bt,
    const float* __restrict__ bias, const float* __restrict__ res,
    float* __restrict__ Cf, unsigned short* __restrict__ Cb,
    int M, int N, int K) {
  __shared__ unsigned short As[128][72];
  __shared__ unsigned short Bs[128][72];
  int tid = threadIdx.x;
  int w = tid >> 6, lane = tid & 63, g = lane >> 4, l16 = lane & 15;
  int wm = w >> 1, wn = w & 1;
  int m0 = blockIdx.y * 128, n0 = blockIdx.x * 128;
  f32x4 acc[4][4] = {};
  for (int k0 = 0; k0 < K; k0 += 64) {
    __syncthreads();
#pragma unroll
    for (int it = 0; it < 4; it++) {
      int idx = tid + it * 256;
      int r = idx >> 3, ch = idx & 7;
      *(u16x8*)&As[r][ch * 8] = *(const u16x8*)&A[(size_t)(m0 + r) * K + k0 + ch * 8];
      *(u16x8*)&Bs[r][ch * 8] = *(const u16x8*)&Bt[(size_t)(n0 + r) * K + k0 + ch * 8];
    }
    __syncthreads();
#pragma unroll
    for (int ks = 0; ks < 2; ks++) {
      short8_t af[4], bf[4];
#pragma unroll
      for (int i = 0; i < 4; i++) {
        af[i] = *(const short8_t*)&As[wm * 64 + i * 16 + l16][ks * 32 + g * 8];
        bf[i] = *(const short8_t*)&Bs[wn * 64 + i * 16 + l16][ks * 32 + g * 8];
      }
#pragma unroll
      for (int mi = 0; mi < 4; mi++)
#pragma unroll
        for (int ni = 0; ni < 4; ni++)
          acc[mi][ni] = __builtin_amdgcn_mfma_f32_16x16x32_bf16(af[mi], bf[ni], acc[mi][ni], 0, 0, 0);
    }
  }
#pragma unroll
  for (int mi = 0; mi < 4; mi++) {
#pragma unroll
    for (int ni = 0; ni < 4; ni++) {
      int n = n0 + wn * 64 + ni * 16 + l16;
      float bv = 0.f;
      if (EPI != 0) bv = bias[n];
#pragma unroll
      for (int r = 0; r < 4; r++) {
        int m = m0 + wm * 64 + mi * 16 + g * 4 + r;
        float c = acc[mi][ni][r] + bv;
        if (EPI == 2) c += res[(size_t)m * N + n];
        if (EPI == 3) c = 0.5f * c * (1.f + erff(c * 0.70710678118f));
        if (OUTM & 1) Cf[(size_t)m * N + n] = c;
        if (OUTM & 2) Cb[(size_t)m * N + n] = f2bf_hw(c);
      }
    }
  }
}

// ============ MHSA via MFMA bf16, flash-style; V via hardware transpose-read ============
__global__ __launch_bounds__(256) void k_attn_mfma(const unsigned short* __restrict__ qkv,
    unsigned short* __restrict__ o) {
  __shared__ unsigned short Ks[64][72];     // [key][dh]
  __shared__ unsigned short Vs[4608];       // subtiled [k>>2][d>>4][k&3][d&15], dd-stride 72, kk-stride 288
  __shared__ unsigned short Plb[4][16][72]; // per-wave P (bf16, A-frag-ready rows)
  int qt = blockIdx.x, h = blockIdx.y, b = blockIdx.z;
  int tid = threadIdx.x;
  int w = tid >> 6, lane = tid & 63;
  int g = lane >> 4, l16 = lane & 15;
  const unsigned short* base  = qkv + (size_t)b * Sc * E3;
  const unsigned short* kbase = base + Ec + h * 64;
  const unsigned short* vbase = base + 2 * Ec + h * 64;
  int q0 = qt * 64 + w * 16;

  // Q frags, pre-scaled by exact pow2 1/sqrt(64)
  short8_t qf[2];
#pragma unroll
  for (int ks = 0; ks < 2; ks++) {
    short8_t f = *(const short8_t*)&base[(size_t)(q0 + l16) * E3 + h * 64 + ks * 32 + g * 8];
#pragma unroll
    for (int e = 0; e < 8; e++)
      f[e] = (short)f2bf_hw(bf2f((unsigned short)f[e]) * 0.125f);
    qf[ks] = f;
  }

  f32x4 o_acc[4] = {};
  float m_r[4] = {-1e30f, -1e30f, -1e30f, -1e30f};
  float l_r[4] = {};

  for (int kt = 0; kt < 16; kt++) {
    __syncthreads();
    // stage K rows + V subtiled, both fully coalesced u16x8
#pragma unroll
    for (int it = 0; it < 2; it++) {
      int idx = tid + it * 256;
      int r = idx >> 3, ch = idx & 7;
      *(u16x8*)&Ks[r][ch * 8] = *(const u16x8*)&kbase[(size_t)(kt * 64 + r) * E3 + ch * 8];
      int voff = (r >> 2) * 288 + (ch >> 1) * 72 + (r & 3) * 16 + (ch & 1) * 8;
      *(u16x8*)&Vs[voff] = *(const u16x8*)&vbase[(size_t)(kt * 64 + r) * E3 + ch * 8];
    }
    __syncthreads();

    // S = Q @ K^T
    f32x4 s_acc[4] = {};
#pragma unroll
    for (int nt = 0; nt < 4; nt++) {
#pragma unroll
      for (int ks = 0; ks < 2; ks++) {
        short8_t kf = *(const short8_t*)&Ks[nt * 16 + l16][ks * 32 + g * 8];
        s_acc[nt] = __builtin_amdgcn_mfma_f32_16x16x32_bf16(qf[ks], kf, s_acc[nt], 0, 0, 0);
      }
    }

    // online softmax; C-layout row=(g*4+r), col=l16+16*nt
#pragma unroll
    for (int r = 0; r < 4; r++) {
      float mx = fmaxf(fmaxf(s_acc[0][r], s_acc[1][r]), fmaxf(s_acc[2][r], s_acc[3][r]));
#pragma unroll
      for (int off = 8; off; off >>= 1) mx = fmaxf(mx, __shfl_xor(mx, off));
      float mn = fmaxf(m_r[r], mx);
      float sc = __expf(m_r[r] - mn);
      m_r[r] = mn;
      l_r[r] *= sc;
#pragma unroll
      for (int dt = 0; dt < 4; dt++) o_acc[dt][r] *= sc;
      float ts = 0.f;
#pragma unroll
      for (int nt = 0; nt < 4; nt++) {
        float p = __expf(s_acc[nt][r] - mn);
        s_acc[nt][r] = p;
        ts += p;
      }
#pragma unroll
      for (int off = 8; off; off >>= 1) ts += __shfl_xor(ts, off);
      l_r[r] += ts;
    }

    // P (C-layout) -> bf16 LDS rows (A-frag-ready), wave-private
#pragma unroll
    for (int nt = 0; nt < 4; nt++)
#pragma unroll
      for (int r = 0; r < 4; r++)
        Plb[w][g * 4 + r][nt * 16 + l16] = f2bf_hw(s_acc[nt][r]);

    // O += P @ V ; V B-frags via ds_read_b64_tr_b16 from subtiled Vs
#pragma unroll
    for (int ks = 0; ks < 2; ks++) {
      short8_t pf = *(const short8_t*)&Plb[w][l16][ks * 32 + g * 8];
      short4_t lo0, lo1, lo2, lo3, hi0, hi1, hi2, hi3;
      unsigned a0 = (unsigned)(uintptr_t)&Vs[(ks * 8 + g * 2) * 288 + 0 * 72 + l16] * 1u;
      unsigned a1 = a0 + 144, a2 = a0 + 288, a3 = a0 + 432;   // dt*72 elems = 144B
      asm volatile("ds_read_b64_tr_b16 %0, %1" : "=v"(lo0) : "v"(a0));
      asm volatile("ds_read_b64_tr_b16 %0, %1 offset:576" : "=v"(hi0) : "v"(a0));
      asm volatile("ds_read_b64_tr_b16 %0, %1" : "=v"(lo1) : "v"(a1));
      asm volatile("ds_read_b64_tr_b16 %0, %1 offset:576" : "=v"(hi1) : "v"(a1));
      asm volatile("ds_read_b64_tr_b16 %0, %1" : "=v"(lo2) : "v"(a2));
      asm volatile("ds_read_b64_tr_b16 %0, %1 offset:576" : "=v"(hi2) : "v"(a2));
      asm volatile("ds_read_b64_tr_b16 %0, %1" : "=v"(lo3) : "v"(a3));
      asm volatile("ds_read_b64_tr_b16 %0, %1 offset:576" : "=v"(hi3) : "v"(a3));
      asm volatile("s_waitcnt lgkmcnt(0)");
      __builtin_amdgcn_sched_barrier(0);
      short4_t lo[4] = {lo0, lo1, lo2, lo3};
      short4_t hi[4] = {hi0, hi1, hi2, hi3};
#pragma unroll
      for (int dt = 0; dt < 4; dt++) {
        short8_t vf;
#pragma unroll
        for (int e = 0; e < 4; e++) { vf[e] = lo[dt][e]; vf[4 + e] = hi[dt][e]; }
        o_acc[dt] = __builtin_amdgcn_mfma_f32_16x16x32_bf16(pf, vf, o_acc[dt], 0, 0, 0);
      }
    }
  }

  unsigned short* obase = o + (size_t)(b * Sc + q0) * Ec + h * 64;
#pragma unroll
  for (int r = 0; r < 4; r++) {
    float inv = 1.f / l_r[r];
    int qrow = g * 4 + r;
#pragma unroll
    for (int dt = 0; dt < 4; dt++)
      obase[(size_t)qrow * Ec + dt * 16 + l16] = f2bf_hw(o_acc[dt][r] * inv);
  }
}

// ============ LN over rows of E=768 (row-major outs) ============
// MODE 0: bf16 out only. MODE 2: f32 + bf16 out.
template<int MODE>
__global__ __launch_bounds__(256) void k_lnrow(const float* __restrict__ in,
    const float* __restrict__ g, const float* __restrict__ bt,
    float* __restrict__ outf, unsigned short* __restrict__ outb) {
  int row = blockIdx.x;
  int tid = threadIdx.x;
  __shared__ float buf[Ec];
  __shared__ float rsum[4], rss[4];
  float sum = 0.f, ss = 0.f;
  for (int i = tid; i < Ec; i += 256) {
    float v = in[(size_t)row * Ec + i];
    buf[i] = v; sum += v; ss += v * v;
  }
#pragma unroll
  for (int off = 32; off > 0; off >>= 1) {
    sum += __shfl_xor(sum, off); ss += __shfl_xor(ss, off);
  }
  if ((tid & 63) == 0) { rsum[tid >> 6] = sum; rss[tid >> 6] = ss; }
  __syncthreads();
  sum = rsum[0] + rsum[1] + rsum[2] + rsum[3];
  ss = rss[0] + rss[1] + rss[2] + rss[3];
  float mean = sum / Ec;
  float rstd = rsqrtf(ss / Ec - mean * mean + 1e-5f);
  for (int i = tid; i < Ec; i += 256) {
    float v = (buf[i] - mean) * rstd * g[i] + bt[i];
    if (MODE == 2) outf[(size_t)row * Ec + i] = v;
    outb[(size_t)row * Ec + i] = f2bf_hw(v);
  }
}

// ============ final LN: out = LN(n3+mlp) transposed to [B,E,H,W]; 16 rows/block, 64B col writes ============
__global__ __launch_bounds__(256) void k_lnout(const float* __restrict__ in,
    const float* __restrict__ res, const float* __restrict__ g,
    const float* __restrict__ bt, float* __restrict__ out) {
  int r0 = blockIdx.x * 16;          // 256 blocks
  int b = r0 >> 10, s0 = r0 & 1023;
  __shared__ float Tr[16][772];
  __shared__ float mean_s[16], rstd_s[16];
  int rl = threadIdx.x >> 4, el = threadIdx.x & 15;
  const float* ip = in + (size_t)(r0 + rl) * Ec;
  const float* rp = res + (size_t)(r0 + rl) * Ec;
  float sum = 0.f, ss = 0.f;
  for (int i = el; i < Ec; i += 16) {
    float v = ip[i] + rp[i];
    Tr[rl][i] = v; sum += v; ss += v * v;
  }
#pragma unroll
  for (int off = 8; off; off >>= 1) {
    sum += __shfl_xor(sum, off); ss += __shfl_xor(ss, off);
  }
  if (el == 0) {
    float mean = sum / Ec;
    mean_s[rl] = mean;
    rstd_s[rl] = rsqrtf(ss / Ec - mean * mean + 1e-5f);
  }
  __syncthreads();
  int sl = threadIdx.x & 15, il = threadIdx.x >> 4;
  float mean = mean_s[sl], rstd = rstd_s[sl];
  for (int i = il; i < Ec; i += 16)
    out[((size_t)b * Ec + i) * Sc + s0 + sl] = (Tr[sl][i] - mean) * rstd * g[i] + bt[i];
}

// ============ per-node attention coefficients a_s, a_d ============
__global__ __launch_bounds__(256) void k_asd(const float* __restrict__ hN,
    const float* __restrict__ att_src, const float* __restrict__ att_dst,
    float* __restrict__ a_s, float* __restrict__ a_d) {
  int n = blockIdx.x * 4 + (threadIdx.x >> 6);
  int lane = threadIdx.x & 63;
  const float* hrow = hN + (size_t)n * Ec;
#pragma unroll
  for (int h = 0; h < GHEAD; h++) {
    float ps = 0.f, pd = 0.f;
    for (int d = lane; d < DGAT; d += 64) {
      float v = hrow[h * DGAT + d];
      ps += v * att_src[h * DGAT + d];
      pd += v * att_dst[h * DGAT + d];
    }
#pragma unroll
    for (int off = 32; off > 0; off >>= 1) {
      ps += __shfl_xor(ps, off); pd += __shfl_xor(pd, off);
    }
    if (lane == 0) { a_s[n * GHEAD + h] = ps; a_d[n * GHEAD + h] = pd; }
  }
}

// ============ GAT stencil ============
__global__ __launch_bounds__(256) void k_gat(const float* __restrict__ hN,
    const float* __restrict__ a_s, const float* __restrict__ a_d,
    const float* __restrict__ x_attn, const float* __restrict__ gat_b,
    float* __restrict__ x_after) {
  int n = blockIdx.x;
  int b = n >> 10, s = n & 1023, r = s >> 5, c = s & 31;
  __shared__ int nbr[9];
  __shared__ float alpha[GHEAD][9];
  int tid = threadIdx.x;
  if (tid < 9) {
    int dr = tid / 3 - 1, dc = tid % 3 - 1;
    int rr = r + dr, cc = c + dc;
    int ok = (rr >= 0 && rr < 32 && cc >= 0 && cc < 32);
    if (dr == -1 && dc == 1 && cc == 31) ok = 0;
    if (dr == 1 && dc == -1 && c == 31) ok = 0;
    nbr[tid] = ok ? ((b << 10) + (rr << 5) + cc) : -1;
  }
  __syncthreads();
  if (tid < GHEAD) {
    int h = tid;
    float ad = a_d[n * GHEAD + h];
    float ev[9]; float m = -1e30f;
#pragma unroll
    for (int j = 0; j < 9; j++) {
      if (nbr[j] >= 0) {
        float e = a_s[nbr[j] * GHEAD + h] + ad;
        e = e > 0.f ? e : 0.2f * e;
        ev[j] = e; m = fmaxf(m, e);
      } else ev[j] = -1e30f;
    }
    float den = 0.f;
#pragma unroll
    for (int j = 0; j < 9; j++) {
      float x = (nbr[j] >= 0) ? expf(ev[j] - m) : 0.f;
      ev[j] = x; den += x;
    }
    float inv = 1.f / den;
#pragma unroll
    for (int j = 0; j < 9; j++) alpha[h][j] = ev[j] * inv;
  }
  __syncthreads();
  for (int e = tid; e < Ec; e += 256) {
    int h = e / DGAT;
    float acc = 0.f;
#pragma unroll
    for (int j = 0; j < 9; j++) {
      int nj = nbr[j];
      if (nj >= 0) acc += alpha[h][j] * hN[(size_t)nj * Ec + e];
    }
    float v = acc + gat_b[e];
    v = v > 0.f ? v : expf(v) - 1.f;
    x_after[(size_t)n * Ec + e] = x_attn[(size_t)n * Ec + e] + v;
  }
}

extern "C" void kernel_launch(void* const* d_in, const int* in_sizes, int n_in,
                              void* d_out, int out_size, void* d_ws, size_t ws_size,
                              hipStream_t stream) {
  (void)in_sizes; (void)n_in; (void)out_size; (void)ws_size;
  const float* x      = (const float*)d_in[0];
  const float* ln1_g  = (const float*)d_in[1];
  const float* ln1_b  = (const float*)d_in[2];
  const float* proj_w = (const float*)d_in[3];
  const float* proj_b = (const float*)d_in[4];
  const float* wqkv   = (const float*)d_in[5];
  const float* bqkv   = (const float*)d_in[6];
  const float* wo     = (const float*)d_in[7];
  const float* bo     = (const float*)d_in[8];
  const float* ln2_g  = (const float*)d_in[9];
  const float* ln2_b  = (const float*)d_in[10];
  const float* gp_w   = (const float*)d_in[11];
  const float* gp_b   = (const float*)d_in[12];
  const float* gat_w  = (const float*)d_in[13];
  const float* att_src= (const float*)d_in[14];
  const float* att_dst= (const float*)d_in[15];
  const float* gat_b  = (const float*)d_in[16];
  const float* ln3_g  = (const float*)d_in[17];
  const float* ln3_b  = (const float*)d_in[18];
  const float* mlp_w1 = (const float*)d_in[19];
  const float* mlp_b1 = (const float*)d_in[20];
  const float* mlp_w2 = (const float*)d_in[21];
  const float* mlp_b2 = (const float*)d_in[22];
  const float* fn_g   = (const float*)d_in[23];
  const float* fn_b   = (const float*)d_in[24];
  float* out = (float*)d_out;

  // ---- workspace layout ----
  char* p = (char*)d_ws;
  auto alloc = [&](size_t bytes) { char* q = p; p += (bytes + 255) & ~(size_t)255; return q; };
  char* regA      = alloc((size_t)Ntok * E3 * 2);            // n1_bf -> qkv_bf
  unsigned short* n1_bf  = (unsigned short*)regA;
  unsigned short* qkv_bf = (unsigned short*)regA;
  unsigned short* proj_wt = (unsigned short*)alloc((size_t)Ec * Cc * 2);
  unsigned short* wqkv_t  = (unsigned short*)alloc((size_t)E3 * Ec * 2);
  unsigned short* wo_t    = (unsigned short*)alloc((size_t)Ec * Ec * 2);
  unsigned short* gp_t    = (unsigned short*)alloc((size_t)Ec * Ec * 2);
  unsigned short* gat_t   = (unsigned short*)alloc((size_t)Ec * Ec * 2);
  unsigned short* m1_t    = (unsigned short*)alloc((size_t)Ec * Ec * 2);
  unsigned short* m2_t    = (unsigned short*)alloc((size_t)Ec * Ec * 2);
  float* v_in   = (float*)alloc((size_t)Ntok * Ec * 4);
  unsigned short* v_in_bf = (unsigned short*)alloc((size_t)Ntok * Ec * 2);
  unsigned short* regE    = (unsigned short*)alloc((size_t)Ntok * Ec * 2); // o_bf -> h1_bf
  float* regF   = (float*)alloc((size_t)Ntok * Ec * 4);      // x_attn -> n3 f32
  unsigned short* regG    = (unsigned short*)alloc((size_t)Ntok * Ec * 2); // n2_bf -> n3_bf
  unsigned short* g_bf    = (unsigned short*)alloc((size_t)Ntok * Ec * 2);
  float* hN     = (float*)alloc((size_t)Ntok * Ec * 4);
  float* regJ   = (float*)alloc((size_t)Ntok * Ec * 4);      // x_after -> mlp_out
  float* a_s    = (float*)alloc((size_t)Ntok * GHEAD * 4);
  float* a_d    = (float*)alloc((size_t)Ntok * GHEAD * 4);

  unsigned short* o_bf   = regE;
  unsigned short* h1_bf  = regE;
  float* x_attn = regF;
  float* n3_f   = regF;
  unsigned short* n2_bf  = regG;
  unsigned short* n3_bf  = regG;
  float* x_after = regJ;
  float* mlp_out = regJ;

  // 0) weights -> transposed bf16
  WtArgs wa;
  wa.src[0] = proj_w; wa.dst[0] = proj_wt; wa.K[0] = Cc; wa.N[0] = Ec;
  wa.src[1] = wqkv;   wa.dst[1] = wqkv_t;  wa.K[1] = Ec; wa.N[1] = E3;
  wa.src[2] = wo;     wa.dst[2] = wo_t;    wa.K[2] = Ec; wa.N[2] = Ec;
  wa.src[3] = gp_w;   wa.dst[3] = gp_t;    wa.K[3] = Ec; wa.N[3] = Ec;
  wa.src[4] = gat_w;  wa.dst[4] = gat_t;   wa.K[4] = Ec; wa.N[4] = Ec;
  wa.src[5] = mlp_w1; wa.dst[5] = m1_t;    wa.K[5] = Ec; wa.N[5] = Ec;
  wa.src[6] = mlp_w2; wa.dst[6] = m2_t;    wa.K[6] = Ec; wa.N[6] = Ec;
  int cum = 0;
  for (int i = 0; i < 7; i++) { wa.off[i] = cum; cum += (wa.K[i] >> 5) * (wa.N[i] >> 5); }
  wa.off[7] = cum;
  k_wt<<<cum, 256, 0, stream>>>(wa);

  // 1) LN1 -> bf16 [M][C]
  k_ln1_bf<<<256, 256, 0, stream>>>(x, ln1_g, ln1_b, n1_bf);
  // 2) v_in = n1 @ proj_w + proj_b  (f32 + bf16 out)
  gemm_bf16<1, 3><<<dim3(Ec / 128, Ntok / 128), 256, 0, stream>>>(
      n1_bf, proj_wt, proj_b, nullptr, v_in, v_in_bf, Ntok, Ec, Cc);
  // 3) qkv = v_in @ wqkv + bqkv  (bf16 out)
  gemm_bf16<1, 2><<<dim3(E3 / 128, Ntok / 128), 256, 0, stream>>>(
      v_in_bf, wqkv_t, bqkv, nullptr, nullptr, qkv_bf, Ntok, E3, Ec);
  // 4) attention
  k_attn_mfma<<<dim3(16, NHEAD, Bc), 256, 0, stream>>>(qkv_bf, o_bf);
  // 5) x_attn = v_in + o @ wo + bo  (f32)
  gemm_bf16<2, 1><<<dim3(Ec / 128, Ntok / 128), 256, 0, stream>>>(
      o_bf, wo_t, bo, v_in, x_attn, nullptr, Ntok, Ec, Ec);
  // 6) n2 = LN(x_attn) -> bf16
  k_lnrow<0><<<Ntok, 256, 0, stream>>>(x_attn, ln2_g, ln2_b, nullptr, n2_bf);
  // 7) g = n2 @ gp_w + gp_b -> bf16
  gemm_bf16<1, 2><<<dim3(Ec / 128, Ntok / 128), 256, 0, stream>>>(
      n2_bf, gp_t, gp_b, nullptr, nullptr, g_bf, Ntok, Ec, Ec);
  // 8) hN = g @ gat_w -> f32
  gemm_bf16<0, 1><<<dim3(Ec / 128, Ntok / 128), 256, 0, stream>>>(
      g_bf, gat_t, nullptr, nullptr, hN, nullptr, Ntok, Ec, Ec);
  // 9) a_s, a_d
  k_asd<<<Ntok / 4, 256, 0, stream>>>(hN, att_src, att_dst, a_s, a_d);
  // 10) GAT aggregate + elu + residual -> x_after
  k_gat<<<Ntok, 256, 0, stream>>>(hN, a_s, a_d, x_attn, gat_b, x_after);
  // 11) n3 = LN(x_after) -> f32 + bf16
  k_lnrow<2><<<Ntok, 256, 0, stream>>>(x_after, ln3_g, ln3_b, n3_f, n3_bf);
  // 12) h1 = gelu(n3 @ mlp_w1 + mlp_b1) -> bf16
  gemm_bf16<3, 2><<<dim3(Ec / 128, Ntok / 128), 256, 0, stream>>>(
      n3_bf, m1_t, mlp_b1, nullptr, nullptr, h1_bf, Ntok, Ec, Ec);
  // 13) mlp = h1 @ mlp_w2 + mlp_b2 -> f32
  gemm_bf16<1, 1><<<dim3(Ec / 128, Ntok / 128), 256, 0, stream>>>(
      h1_bf, m2_t, mlp_b2, nullptr, mlp_out, nullptr, Ntok, Ec, Ec);
  // 14) out = LN(n3 + mlp), transposed to [B,E,H,W]
  k_lnout<<<256, 256, 0, stream>>>(n3_f, mlp_out, fn_g, fn_b, out);
}

// Round 5
// 314.599 us; speedup vs baseline: 7.4077x; 1.1080x over previous
//
#include <hip/hip_runtime.h>

// ---- problem constants ----
constexpr int Bc = 4;
constexpr int Cc = 2048;
constexpr int Sc = 1024;     // H*W = 32*32
constexpr int Ntok = 4096;   // B*S
constexpr int Ec = 768;
constexpr int E3 = 2304;
constexpr int NHEAD = 12;
constexpr int GHEAD = 4;
constexpr int DGAT = 192;

typedef __attribute__((ext_vector_type(8))) short short8_t;   // bf16x8 MFMA frag
typedef __attribute__((ext_vector_type(4))) short short4_t;
typedef __attribute__((ext_vector_type(8))) unsigned short u16x8;
typedef __attribute__((ext_vector_type(4))) float f32x4;

// software RNE f32->bf16 (v_cvt_pk_bf16_f32 appears to round toward zero: absmax 2x)
__device__ inline unsigned short f2bf(float f) {
  unsigned int u = __builtin_bit_cast(unsigned int, f);
  u += 0x7FFFu + ((u >> 16) & 1u);
  return (unsigned short)(u >> 16);
}
// hw packed cvt — used ONLY for attention P fragments (softmax-normalized, bias bounded)
__device__ inline unsigned short f2bf_hw(float f) {
  unsigned int r;
  asm("v_cvt_pk_bf16_f32 %0, %1, %1" : "=v"(r) : "v"(f));
  return (unsigned short)r;
}
__device__ inline float bf2f(unsigned short h) {
  unsigned int u = ((unsigned int)h) << 16;
  return __builtin_bit_cast(float, u);
}

// ============ fused weight transpose+bf16: [K][N] f32 -> [N][K] bf16, 7 weights ============
struct WtArgs {
  const float* src[7];
  unsigned short* dst[7];
  int K[7], N[7];
  int off[8];
};
__global__ __launch_bounds__(256) void k_wt(WtArgs a) {
  __shared__ float t[32][33];
  int bid = blockIdx.x;
  int w = 0;
  while (w < 6 && bid >= a.off[w + 1]) ++w;
  int local = bid - a.off[w];
  int K = a.K[w], N = a.N[w];
  int ntn = N >> 5;
  int tk = local / ntn, tn = local - tk * ntn;
  int k0 = tk * 32, n0 = tn * 32;
  int tx = threadIdx.x & 31, ty = threadIdx.x >> 5;
  const float* src = a.src[w];
#pragma unroll
  for (int i = 0; i < 4; i++)
    t[ty + i * 8][tx] = src[(size_t)(k0 + ty + i * 8) * N + n0 + tx];
  __syncthreads();
  unsigned short* dst = a.dst[w];
#pragma unroll
  for (int i = 0; i < 4; i++)
    dst[(size_t)(n0 + ty + i * 8) * K + k0 + tx] = f2bf(t[tx][ty + i * 8]);
}

// ============ LN1 pass A: partial sums over 256-c chunks ============
// grid (8 cc, 64 st, 4 b); writes psum/pss[bs][8]
__global__ __launch_bounds__(256) void k_ln1_stats(const float* __restrict__ x,
    float* __restrict__ psum, float* __restrict__ pss) {
  int cc = blockIdx.x, st = blockIdx.y, b = blockIdx.z;
  int sl = threadIdx.x & 15, cl = threadIdx.x >> 4;
  int s = st * 16 + sl;
  const float* xb = x + (size_t)b * Cc * Sc + s;
  float sum = 0.f, ss = 0.f;
#pragma unroll
  for (int t = 0; t < 16; t++) {
    int c = cc * 256 + cl + t * 16;
    float v = xb[(size_t)c * Sc];
    sum += v; ss += v * v;
  }
  __shared__ float rs0[16][17], rs1[16][17];
  rs0[cl][sl] = sum; rs1[cl][sl] = ss;
  __syncthreads();
  if (cl == 0) {
    float a = 0.f, q = 0.f;
#pragma unroll
    for (int i = 0; i < 16; i++) { a += rs0[i][sl]; q += rs1[i][sl]; }
    size_t bs = (size_t)(b * Sc + st * 16 + sl);
    psum[bs * 8 + cc] = a;
    pss[bs * 8 + cc] = q;
  }
}

// ============ LN1 pass B: normalize + transpose to bf16 [M][C], one 128-c chunk/block ============
// grid (16 cc, 64 st, 4 b)
__global__ __launch_bounds__(256) void k_ln1_norm(const float* __restrict__ x,
    const float* __restrict__ g, const float* __restrict__ bt,
    const float* __restrict__ psum, const float* __restrict__ pss,
    unsigned short* __restrict__ out) {
  int cc = blockIdx.x, st = blockIdx.y, b = blockIdx.z;
  int sl = threadIdx.x & 15, cl = threadIdx.x >> 4;
  int s = st * 16 + sl;
  // gather partials: thread group t8 = cl handles row sl
  __shared__ float red[16][17];
  __shared__ float mean_s[16], rstd_s[16];
  int t8 = cl;
  size_t bsrow = (size_t)(b * Sc + st * 16 + sl);
  float v = (t8 < 8) ? psum[bsrow * 8 + t8] : pss[bsrow * 8 + (t8 - 8)];
  red[t8][sl] = v;
  __syncthreads();
  if (threadIdx.x < 16) {
    float s0 = 0.f, s1 = 0.f;
#pragma unroll
    for (int i = 0; i < 8; i++) { s0 += red[i][threadIdx.x]; s1 += red[i + 8][threadIdx.x]; }
    float mean = s0 / Cc;
    mean_s[threadIdx.x] = mean;
    rstd_s[threadIdx.x] = rsqrtf(s1 / Cc - mean * mean + 1e-5f);
  }
  __syncthreads();
  float mean = mean_s[sl], rstd = rstd_s[sl];
  const float* xb = x + (size_t)b * Cc * Sc + s;
  __shared__ unsigned short Tc[16][136];
  int cb = cc * 128;
#pragma unroll
  for (int t = 0; t < 8; t++) {
    int c = cb + cl + t * 16;
    float xv = xb[(size_t)c * Sc];
    Tc[sl][cl + t * 16] = f2bf((xv - mean) * rstd * g[c] + bt[c]);
  }
  __syncthreads();
  int rl = threadIdx.x >> 4, el = threadIdx.x & 15;
  unsigned short* ob = out + ((size_t)(b * Sc) + st * 16 + rl) * Cc + cb;
  *(u16x8*)&ob[el * 8] = *(const u16x8*)&Tc[rl][el * 8];
}

// ============ bf16 MFMA GEMM: C[M][N] = A[M][K] @ Bt[N][K]^T ============
template<int EPI, int OUTM>
__global__ __launch_bounds__(256) void gemm_bf16(
    const unsigned short* __restrict__ A, const unsigned short* __restrict__ Bt,
    const float* __restrict__ bias, const float* __restrict__ res,
    float* __restrict__ Cf, unsigned short* __restrict__ Cb,
    int M, int N, int K) {
  __shared__ unsigned short As[128][72];
  __shared__ unsigned short Bs[128][72];
  int tid = threadIdx.x;
  int w = tid >> 6, lane = tid & 63, g = lane >> 4, l16 = lane & 15;
  int wm = w >> 1, wn = w & 1;
  int m0 = blockIdx.y * 128, n0 = blockIdx.x * 128;
  f32x4 acc[4][4] = {};
  for (int k0 = 0; k0 < K; k0 += 64) {
    __syncthreads();
#pragma unroll
    for (int it = 0; it < 4; it++) {
      int idx = tid + it * 256;
      int r = idx >> 3, ch = idx & 7;
      *(u16x8*)&As[r][ch * 8] = *(const u16x8*)&A[(size_t)(m0 + r) * K + k0 + ch * 8];
      *(u16x8*)&Bs[r][ch * 8] = *(const u16x8*)&Bt[(size_t)(n0 + r) * K + k0 + ch * 8];
    }
    __syncthreads();
#pragma unroll
    for (int ks = 0; ks < 2; ks++) {
      short8_t af[4], bf[4];
#pragma unroll
      for (int i = 0; i < 4; i++) {
        af[i] = *(const short8_t*)&As[wm * 64 + i * 16 + l16][ks * 32 + g * 8];
        bf[i] = *(const short8_t*)&Bs[wn * 64 + i * 16 + l16][ks * 32 + g * 8];
      }
#pragma unroll
      for (int mi = 0; mi < 4; mi++)
#pragma unroll
        for (int ni = 0; ni < 4; ni++)
          acc[mi][ni] = __builtin_amdgcn_mfma_f32_16x16x32_bf16(af[mi], bf[ni], acc[mi][ni], 0, 0, 0);
    }
  }
#pragma unroll
  for (int mi = 0; mi < 4; mi++) {
#pragma unroll
    for (int ni = 0; ni < 4; ni++) {
      int n = n0 + wn * 64 + ni * 16 + l16;
      float bv = 0.f;
      if (EPI != 0) bv = bias[n];
#pragma unroll
      for (int r = 0; r < 4; r++) {
        int m = m0 + wm * 64 + mi * 16 + g * 4 + r;
        float c = acc[mi][ni][r] + bv;
        if (EPI == 2) c += res[(size_t)m * N + n];
        if (EPI == 3) c = 0.5f * c * (1.f + erff(c * 0.70710678118f));
        if (OUTM & 1) Cf[(size_t)m * N + n] = c;
        if (OUTM & 2) Cb[(size_t)m * N + n] = f2bf(c);
      }
    }
  }
}

// ============ MHSA via MFMA bf16, flash-style; V via hardware transpose-read ============
__global__ __launch_bounds__(256) void k_attn_mfma(const unsigned short* __restrict__ qkv,
    unsigned short* __restrict__ o) {
  __shared__ unsigned short Ks[64][72];     // [key][dh]
  __shared__ unsigned short Vs[4608];       // subtiled, dd-stride 72, kk-stride 288
  __shared__ unsigned short Plb[4][16][72]; // per-wave P (bf16, A-frag-ready rows)
  int qt = blockIdx.x, h = blockIdx.y, b = blockIdx.z;
  int tid = threadIdx.x;
  int w = tid >> 6, lane = tid & 63;
  int g = lane >> 4, l16 = lane & 15;
  const unsigned short* base  = qkv + (size_t)b * Sc * E3;
  const unsigned short* kbase = base + Ec + h * 64;
  const unsigned short* vbase = base + 2 * Ec + h * 64;
  int q0 = qt * 64 + w * 16;

  // Q frags, pre-scaled by exact pow2 1/sqrt(64) (no rounding: exponent shift)
  short8_t qf[2];
#pragma unroll
  for (int ks = 0; ks < 2; ks++) {
    short8_t f = *(const short8_t*)&base[(size_t)(q0 + l16) * E3 + h * 64 + ks * 32 + g * 8];
#pragma unroll
    for (int e = 0; e < 8; e++)
      f[e] = (short)f2bf(bf2f((unsigned short)f[e]) * 0.125f);
    qf[ks] = f;
  }

  f32x4 o_acc[4] = {};
  float m_r[4] = {-1e30f, -1e30f, -1e30f, -1e30f};
  float l_r[4] = {};

  for (int kt = 0; kt < 16; kt++) {
    __syncthreads();
#pragma unroll
    for (int it = 0; it < 2; it++) {
      int idx = tid + it * 256;
      int r = idx >> 3, ch = idx & 7;
      *(u16x8*)&Ks[r][ch * 8] = *(const u16x8*)&kbase[(size_t)(kt * 64 + r) * E3 + ch * 8];
      int voff = (r >> 2) * 288 + (ch >> 1) * 72 + (r & 3) * 16 + (ch & 1) * 8;
      *(u16x8*)&Vs[voff] = *(const u16x8*)&vbase[(size_t)(kt * 64 + r) * E3 + ch * 8];
    }
    __syncthreads();

    f32x4 s_acc[4] = {};
#pragma unroll
    for (int nt = 0; nt < 4; nt++) {
#pragma unroll
      for (int ks = 0; ks < 2; ks++) {
        short8_t kf = *(const short8_t*)&Ks[nt * 16 + l16][ks * 32 + g * 8];
        s_acc[nt] = __builtin_amdgcn_mfma_f32_16x16x32_bf16(qf[ks], kf, s_acc[nt], 0, 0, 0);
      }
    }

#pragma unroll
    for (int r = 0; r < 4; r++) {
      float mx = fmaxf(fmaxf(s_acc[0][r], s_acc[1][r]), fmaxf(s_acc[2][r], s_acc[3][r]));
#pragma unroll
      for (int off = 8; off; off >>= 1) mx = fmaxf(mx, __shfl_xor(mx, off));
      float mn = fmaxf(m_r[r], mx);
      float sc = __expf(m_r[r] - mn);
      m_r[r] = mn;
      l_r[r] *= sc;
#pragma unroll
      for (int dt = 0; dt < 4; dt++) o_acc[dt][r] *= sc;
      float ts = 0.f;
#pragma unroll
      for (int nt = 0; nt < 4; nt++) {
        float p = __expf(s_acc[nt][r] - mn);
        s_acc[nt][r] = p;
        ts += p;
      }
#pragma unroll
      for (int off = 8; off; off >>= 1) ts += __shfl_xor(ts, off);
      l_r[r] += ts;
    }

    // P (C-layout) -> bf16 LDS rows (hw cvt ok: softmax-normalized values)
#pragma unroll
    for (int nt = 0; nt < 4; nt++)
#pragma unroll
      for (int r = 0; r < 4; r++)
        Plb[w][g * 4 + r][nt * 16 + l16] = f2bf_hw(s_acc[nt][r]);

#pragma unroll
    for (int ks = 0; ks < 2; ks++) {
      short8_t pf = *(const short8_t*)&Plb[w][l16][ks * 32 + g * 8];
      short4_t lo0, lo1, lo2, lo3, hi0, hi1, hi2, hi3;
      unsigned a0 = (unsigned)(uintptr_t)&Vs[(ks * 8 + g * 2) * 288 + 0 * 72 + l16] * 1u;
      unsigned a1 = a0 + 144, a2 = a0 + 288, a3 = a0 + 432;
      asm volatile("ds_read_b64_tr_b16 %0, %1" : "=v"(lo0) : "v"(a0));
      asm volatile("ds_read_b64_tr_b16 %0, %1 offset:576" : "=v"(hi0) : "v"(a0));
      asm volatile("ds_read_b64_tr_b16 %0, %1" : "=v"(lo1) : "v"(a1));
      asm volatile("ds_read_b64_tr_b16 %0, %1 offset:576" : "=v"(hi1) : "v"(a1));
      asm volatile("ds_read_b64_tr_b16 %0, %1" : "=v"(lo2) : "v"(a2));
      asm volatile("ds_read_b64_tr_b16 %0, %1 offset:576" : "=v"(hi2) : "v"(a2));
      asm volatile("ds_read_b64_tr_b16 %0, %1" : "=v"(lo3) : "v"(a3));
      asm volatile("ds_read_b64_tr_b16 %0, %1 offset:576" : "=v"(hi3) : "v"(a3));
      asm volatile("s_waitcnt lgkmcnt(0)");
      __builtin_amdgcn_sched_barrier(0);
      short4_t lo[4] = {lo0, lo1, lo2, lo3};
      short4_t hi[4] = {hi0, hi1, hi2, hi3};
#pragma unroll
      for (int dt = 0; dt < 4; dt++) {
        short8_t vf;
#pragma unroll
        for (int e = 0; e < 4; e++) { vf[e] = lo[dt][e]; vf[4 + e] = hi[dt][e]; }
        o_acc[dt] = __builtin_amdgcn_mfma_f32_16x16x32_bf16(pf, vf, o_acc[dt], 0, 0, 0);
      }
    }
  }

  unsigned short* obase = o + (size_t)(b * Sc + q0) * Ec + h * 64;
#pragma unroll
  for (int r = 0; r < 4; r++) {
    float inv = 1.f / l_r[r];
    int qrow = g * 4 + r;
#pragma unroll
    for (int dt = 0; dt < 4; dt++)
      obase[(size_t)qrow * Ec + dt * 16 + l16] = f2bf(o_acc[dt][r] * inv);
  }
}

// ============ LN over rows of E=768 (row-major outs) ============
template<int MODE>
__global__ __launch_bounds__(256) void k_lnrow(const float* __restrict__ in,
    const float* __restrict__ g, const float* __restrict__ bt,
    float* __restrict__ outf, unsigned short* __restrict__ outb) {
  int row = blockIdx.x;
  int tid = threadIdx.x;
  __shared__ float buf[Ec];
  __shared__ float rsum[4], rss[4];
  float sum = 0.f, ss = 0.f;
  for (int i = tid; i < Ec; i += 256) {
    float v = in[(size_t)row * Ec + i];
    buf[i] = v; sum += v; ss += v * v;
  }
#pragma unroll
  for (int off = 32; off > 0; off >>= 1) {
    sum += __shfl_xor(sum, off); ss += __shfl_xor(ss, off);
  }
  if ((tid & 63) == 0) { rsum[tid >> 6] = sum; rss[tid >> 6] = ss; }
  __syncthreads();
  sum = rsum[0] + rsum[1] + rsum[2] + rsum[3];
  ss = rss[0] + rss[1] + rss[2] + rss[3];
  float mean = sum / Ec;
  float rstd = rsqrtf(ss / Ec - mean * mean + 1e-5f);
  for (int i = tid; i < Ec; i += 256) {
    float v = (buf[i] - mean) * rstd * g[i] + bt[i];
    if (MODE == 2) outf[(size_t)row * Ec + i] = v;
    outb[(size_t)row * Ec + i] = f2bf(v);
  }
}

// ============ final LN: out = LN(n3+mlp) transposed to [B,E,H,W] ============
__global__ __launch_bounds__(256) void k_lnout(const float* __restrict__ in,
    const float* __restrict__ res, const float* __restrict__ g,
    const float* __restrict__ bt, float* __restrict__ out) {
  int r0 = blockIdx.x * 16;
  int b = r0 >> 10, s0 = r0 & 1023;
  __shared__ float Tr[16][772];
  __shared__ float mean_s[16], rstd_s[16];
  int rl = threadIdx.x >> 4, el = threadIdx.x & 15;
  const float* ip = in + (size_t)(r0 + rl) * Ec;
  const float* rp = res + (size_t)(r0 + rl) * Ec;
  float sum = 0.f, ss = 0.f;
  for (int i = el; i < Ec; i += 16) {
    float v = ip[i] + rp[i];
    Tr[rl][i] = v; sum += v; ss += v * v;
  }
#pragma unroll
  for (int off = 8; off; off >>= 1) {
    sum += __shfl_xor(sum, off); ss += __shfl_xor(ss, off);
  }
  if (el == 0) {
    float mean = sum / Ec;
    mean_s[rl] = mean;
    rstd_s[rl] = rsqrtf(ss / Ec - mean * mean + 1e-5f);
  }
  __syncthreads();
  int sl = threadIdx.x & 15, il = threadIdx.x >> 4;
  float mean = mean_s[sl], rstd = rstd_s[sl];
  for (int i = il; i < Ec; i += 16)
    out[((size_t)b * Ec + i) * Sc + s0 + sl] = (Tr[sl][i] - mean) * rstd * g[i] + bt[i];
}

// ============ per-node attention coefficients a_s, a_d ============
__global__ __launch_bounds__(256) void k_asd(const float* __restrict__ hN,
    const float* __restrict__ att_src, const float* __restrict__ att_dst,
    float* __restrict__ a_s, float* __restrict__ a_d) {
  int n = blockIdx.x * 4 + (threadIdx.x >> 6);
  int lane = threadIdx.x & 63;
  const float* hrow = hN + (size_t)n * Ec;
#pragma unroll
  for (int h = 0; h < GHEAD; h++) {
    float ps = 0.f, pd = 0.f;
    for (int d = lane; d < DGAT; d += 64) {
      float v = hrow[h * DGAT + d];
      ps += v * att_src[h * DGAT + d];
      pd += v * att_dst[h * DGAT + d];
    }
#pragma unroll
    for (int off = 32; off > 0; off >>= 1) {
      ps += __shfl_xor(ps, off); pd += __shfl_xor(pd, off);
    }
    if (lane == 0) { a_s[n * GHEAD + h] = ps; a_d[n * GHEAD + h] = pd; }
  }
}

// ============ GAT stencil ============
__global__ __launch_bounds__(256) void k_gat(const float* __restrict__ hN,
    const float* __restrict__ a_s, const float* __restrict__ a_d,
    const float* __restrict__ x_attn, const float* __restrict__ gat_b,
    float* __restrict__ x_after) {
  int n = blockIdx.x;
  int b = n >> 10, s = n & 1023, r = s >> 5, c = s & 31;
  __shared__ int nbr[9];
  __shared__ float alpha[GHEAD][9];
  int tid = threadIdx.x;
  if (tid < 9) {
    int dr = tid / 3 - 1, dc = tid % 3 - 1;
    int rr = r + dr, cc = c + dc;
    int ok = (rr >= 0 && rr < 32 && cc >= 0 && cc < 32);
    if (dr == -1 && dc == 1 && cc == 31) ok = 0;
    if (dr == 1 && dc == -1 && c == 31) ok = 0;
    nbr[tid] = ok ? ((b << 10) + (rr << 5) + cc) : -1;
  }
  __syncthreads();
  if (tid < GHEAD) {
    int h = tid;
    float ad = a_d[n * GHEAD + h];
    float ev[9]; float m = -1e30f;
#pragma unroll
    for (int j = 0; j < 9; j++) {
      if (nbr[j] >= 0) {
        float e = a_s[nbr[j] * GHEAD + h] + ad;
        e = e > 0.f ? e : 0.2f * e;
        ev[j] = e; m = fmaxf(m, e);
      } else ev[j] = -1e30f;
    }
    float den = 0.f;
#pragma unroll
    for (int j = 0; j < 9; j++) {
      float x = (nbr[j] >= 0) ? expf(ev[j] - m) : 0.f;
      ev[j] = x; den += x;
    }
    float inv = 1.f / den;
#pragma unroll
    for (int j = 0; j < 9; j++) alpha[h][j] = ev[j] * inv;
  }
  __syncthreads();
  for (int e = tid; e < Ec; e += 256) {
    int h = e / DGAT;
    float acc = 0.f;
#pragma unroll
    for (int j = 0; j < 9; j++) {
      int nj = nbr[j];
      if (nj >= 0) acc += alpha[h][j] * hN[(size_t)nj * Ec + e];
    }
    float v = acc + gat_b[e];
    v = v > 0.f ? v : expf(v) - 1.f;
    x_after[(size_t)n * Ec + e] = x_attn[(size_t)n * Ec + e] + v;
  }
}

extern "C" void kernel_launch(void* const* d_in, const int* in_sizes, int n_in,
                              void* d_out, int out_size, void* d_ws, size_t ws_size,
                              hipStream_t stream) {
  (void)in_sizes; (void)n_in; (void)out_size; (void)ws_size;
  const float* x      = (const float*)d_in[0];
  const float* ln1_g  = (const float*)d_in[1];
  const float* ln1_b  = (const float*)d_in[2];
  const float* proj_w = (const float*)d_in[3];
  const float* proj_b = (const float*)d_in[4];
  const float* wqkv   = (const float*)d_in[5];
  const float* bqkv   = (const float*)d_in[6];
  const float* wo     = (const float*)d_in[7];
  const float* bo     = (const float*)d_in[8];
  const float* ln2_g  = (const float*)d_in[9];
  const float* ln2_b  = (const float*)d_in[10];
  const float* gp_w   = (const float*)d_in[11];
  const float* gp_b   = (const float*)d_in[12];
  const float* gat_w  = (const float*)d_in[13];
  const float* att_src= (const float*)d_in[14];
  const float* att_dst= (const float*)d_in[15];
  const float* gat_b  = (const float*)d_in[16];
  const float* ln3_g  = (const float*)d_in[17];
  const float* ln3_b  = (const float*)d_in[18];
  const float* mlp_w1 = (const float*)d_in[19];
  const float* mlp_b1 = (const float*)d_in[20];
  const float* mlp_w2 = (const float*)d_in[21];
  const float* mlp_b2 = (const float*)d_in[22];
  const float* fn_g   = (const float*)d_in[23];
  const float* fn_b   = (const float*)d_in[24];
  float* out = (float*)d_out;

  // ---- workspace layout ----
  char* p = (char*)d_ws;
  auto alloc = [&](size_t bytes) { char* q = p; p += (bytes + 255) & ~(size_t)255; return q; };
  char* regA      = alloc((size_t)Ntok * E3 * 2);            // n1_bf -> qkv_bf
  unsigned short* n1_bf  = (unsigned short*)regA;
  unsigned short* qkv_bf = (unsigned short*)regA;
  unsigned short* proj_wt = (unsigned short*)alloc((size_t)Ec * Cc * 2);
  unsigned short* wqkv_t  = (unsigned short*)alloc((size_t)E3 * Ec * 2);
  unsigned short* wo_t    = (unsigned short*)alloc((size_t)Ec * Ec * 2);
  unsigned short* gp_t    = (unsigned short*)alloc((size_t)Ec * Ec * 2);
  unsigned short* gat_t   = (unsigned short*)alloc((size_t)Ec * Ec * 2);
  unsigned short* m1_t    = (unsigned short*)alloc((size_t)Ec * Ec * 2);
  unsigned short* m2_t    = (unsigned short*)alloc((size_t)Ec * Ec * 2);
  float* v_in   = (float*)alloc((size_t)Ntok * Ec * 4);
  unsigned short* v_in_bf = (unsigned short*)alloc((size_t)Ntok * Ec * 2);
  unsigned short* regE    = (unsigned short*)alloc((size_t)Ntok * Ec * 2); // o_bf -> h1_bf
  float* regF   = (float*)alloc((size_t)Ntok * Ec * 4);      // x_attn -> n3 f32
  unsigned short* regG    = (unsigned short*)alloc((size_t)Ntok * Ec * 2); // n2_bf -> n3_bf
  unsigned short* g_bf    = (unsigned short*)alloc((size_t)Ntok * Ec * 2);
  float* hN     = (float*)alloc((size_t)Ntok * Ec * 4);
  float* regJ   = (float*)alloc((size_t)Ntok * Ec * 4);      // x_after -> mlp_out
  float* a_s    = (float*)alloc((size_t)Ntok * GHEAD * 4);
  float* a_d    = (float*)alloc((size_t)Ntok * GHEAD * 4);
  float* psum   = (float*)alloc((size_t)Ntok * 8 * 4);
  float* pss    = (float*)alloc((size_t)Ntok * 8 * 4);

  unsigned short* o_bf   = regE;
  unsigned short* h1_bf  = regE;
  float* x_attn = regF;
  float* n3_f   = regF;
  unsigned short* n2_bf  = regG;
  unsigned short* n3_bf  = regG;
  float* x_after = regJ;
  float* mlp_out = regJ;

  // 0) weights -> transposed bf16
  WtArgs wa;
  wa.src[0] = proj_w; wa.dst[0] = proj_wt; wa.K[0] = Cc; wa.N[0] = Ec;
  wa.src[1] = wqkv;   wa.dst[1] = wqkv_t;  wa.K[1] = Ec; wa.N[1] = E3;
  wa.src[2] = wo;     wa.dst[2] = wo_t;    wa.K[2] = Ec; wa.N[2] = Ec;
  wa.src[3] = gp_w;   wa.dst[3] = gp_t;    wa.K[3] = Ec; wa.N[3] = Ec;
  wa.src[4] = gat_w;  wa.dst[4] = gat_t;   wa.K[4] = Ec; wa.N[4] = Ec;
  wa.src[5] = mlp_w1; wa.dst[5] = m1_t;    wa.K[5] = Ec; wa.N[5] = Ec;
  wa.src[6] = mlp_w2; wa.dst[6] = m2_t;    wa.K[6] = Ec; wa.N[6] = Ec;
  int cum = 0;
  for (int i = 0; i < 7; i++) { wa.off[i] = cum; cum += (wa.K[i] >> 5) * (wa.N[i] >> 5); }
  wa.off[7] = cum;
  k_wt<<<cum, 256, 0, stream>>>(wa);

  // 1) LN1 two-pass -> bf16 [M][C]
  k_ln1_stats<<<dim3(8, 64, 4), 256, 0, stream>>>(x, psum, pss);
  k_ln1_norm<<<dim3(16, 64, 4), 256, 0, stream>>>(x, ln1_g, ln1_b, psum, pss, n1_bf);
  // 2) v_in = n1 @ proj_w + proj_b  (f32 + bf16 out)
  gemm_bf16<1, 3><<<dim3(Ec / 128, Ntok / 128), 256, 0, stream>>>(
      n1_bf, proj_wt, proj_b, nullptr, v_in, v_in_bf, Ntok, Ec, Cc);
  // 3) qkv = v_in @ wqkv + bqkv  (bf16 out)
  gemm_bf16<1, 2><<<dim3(E3 / 128, Ntok / 128), 256, 0, stream>>>(
      v_in_bf, wqkv_t, bqkv, nullptr, nullptr, qkv_bf, Ntok, E3, Ec);
  // 4) attention
  k_attn_mfma<<<dim3(16, NHEAD, Bc), 256, 0, stream>>>(qkv_bf, o_bf);
  // 5) x_attn = v_in + o @ wo + bo  (f32)
  gemm_bf16<2, 1><<<dim3(Ec / 128, Ntok / 128), 256, 0, stream>>>(
      o_bf, wo_t, bo, v_in, x_attn, nullptr, Ntok, Ec, Ec);
  // 6) n2 = LN(x_attn) -> bf16
  k_lnrow<0><<<Ntok, 256, 0, stream>>>(x_attn, ln2_g, ln2_b, nullptr, n2_bf);
  // 7) g = n2 @ gp_w + gp_b -> bf16
  gemm_bf16<1, 2><<<dim3(Ec / 128, Ntok / 128), 256, 0, stream>>>(
      n2_bf, gp_t, gp_b, nullptr, nullptr, g_bf, Ntok, Ec, Ec);
  // 8) hN = g @ gat_w -> f32
  gemm_bf16<0, 1><<<dim3(Ec / 128, Ntok / 128), 256, 0, stream>>>(
      g_bf, gat_t, nullptr, nullptr, hN, nullptr, Ntok, Ec, Ec);
  // 9) a_s, a_d
  k_asd<<<Ntok / 4, 256, 0, stream>>>(hN, att_src, att_dst, a_s, a_d);
  // 10) GAT aggregate + elu + residual -> x_after
  k_gat<<<Ntok, 256, 0, stream>>>(hN, a_s, a_d, x_attn, gat_b, x_after);
  // 11) n3 = LN(x_after) -> f32 + bf16
  k_lnrow<2><<<Ntok, 256, 0, stream>>>(x_after, ln3_g, ln3_b, n3_f, n3_bf);
  // 12) h1 = gelu(n3 @ mlp_w1 + mlp_b1) -> bf16
  gemm_bf16<3, 2><<<dim3(Ec / 128, Ntok / 128), 256, 0, stream>>>(
      n3_bf, m1_t, mlp_b1, nullptr, nullptr, h1_bf, Ntok, Ec, Ec);
  // 13) mlp = h1 @ mlp_w2 + mlp_b2 -> f32
  gemm_bf16<1, 1><<<dim3(Ec / 128, Ntok / 128), 256, 0, stream>>>(
      h1_bf, m2_t, mlp_b2, nullptr, mlp_out, nullptr, Ntok, Ec, Ec);
  // 14) out = LN(n3 + mlp), transposed to [B,E,H,W]
  k_lnout<<<256, 256, 0, stream>>>(n3_f, mlp_out, fn_g, fn_b, out);
}

// Round 6
// 265.556 us; speedup vs baseline: 8.7758x; 1.1847x over previous
//
#include <hip/hip_runtime.h>

// ---- problem constants ----
constexpr int Bc = 4;
constexpr int Cc = 2048;
constexpr int Sc = 1024;     // H*W = 32*32
constexpr int Ntok = 4096;   // B*S
constexpr int Ec = 768;
constexpr int E3 = 2304;
constexpr int NHEAD = 12;
constexpr int GHEAD = 4;
constexpr int DGAT = 192;

typedef __attribute__((ext_vector_type(8))) short short8_t;   // bf16x8 MFMA frag
typedef __attribute__((ext_vector_type(4))) short short4_t;
typedef __attribute__((ext_vector_type(8))) unsigned short u16x8;
typedef __attribute__((ext_vector_type(4))) float f32x4;

// software RNE f32->bf16 (hw v_cvt_pk_bf16_f32 appears biased; RNE everywhere)
__device__ inline unsigned short f2bf(float f) {
  unsigned int u = __builtin_bit_cast(unsigned int, f);
  u += 0x7FFFu + ((u >> 16) & 1u);
  return (unsigned short)(u >> 16);
}
__device__ inline float bf2f(unsigned short h) {
  unsigned int u = ((unsigned int)h) << 16;
  return __builtin_bit_cast(float, u);
}

// ============ fused weight transpose+bf16: [K][N] f32 -> [N][K] bf16, 7 weights ============
struct WtArgs {
  const float* src[7];
  unsigned short* dst[7];
  int K[7], N[7];
  int off[8];
};
__global__ __launch_bounds__(256) void k_wt(WtArgs a) {
  __shared__ float t[32][33];
  int bid = blockIdx.x;
  int w = 0;
  while (w < 6 && bid >= a.off[w + 1]) ++w;
  int local = bid - a.off[w];
  int K = a.K[w], N = a.N[w];
  int ntn = N >> 5;
  int tk = local / ntn, tn = local - tk * ntn;
  int k0 = tk * 32, n0 = tn * 32;
  int tx = threadIdx.x & 31, ty = threadIdx.x >> 5;
  const float* src = a.src[w];
#pragma unroll
  for (int i = 0; i < 4; i++)
    t[ty + i * 8][tx] = src[(size_t)(k0 + ty + i * 8) * N + n0 + tx];
  __syncthreads();
  unsigned short* dst = a.dst[w];
#pragma unroll
  for (int i = 0; i < 4; i++)
    dst[(size_t)(n0 + ty + i * 8) * K + k0 + tx] = f2bf(t[tx][ty + i * 8]);
}

// ============ LN1 pass A: partial sums over 256-c chunks ============
__global__ __launch_bounds__(256) void k_ln1_stats(const float* __restrict__ x,
    float* __restrict__ psum, float* __restrict__ pss) {
  int cc = blockIdx.x, st = blockIdx.y, b = blockIdx.z;
  int sl = threadIdx.x & 15, cl = threadIdx.x >> 4;
  int s = st * 16 + sl;
  const float* xb = x + (size_t)b * Cc * Sc + s;
  float sum = 0.f, ss = 0.f;
#pragma unroll
  for (int t = 0; t < 16; t++) {
    int c = cc * 256 + cl + t * 16;
    float v = xb[(size_t)c * Sc];
    sum += v; ss += v * v;
  }
  __shared__ float rs0[16][17], rs1[16][17];
  rs0[cl][sl] = sum; rs1[cl][sl] = ss;
  __syncthreads();
  if (cl == 0) {
    float a = 0.f, q = 0.f;
#pragma unroll
    for (int i = 0; i < 16; i++) { a += rs0[i][sl]; q += rs1[i][sl]; }
    size_t bs = (size_t)(b * Sc + st * 16 + sl);
    psum[bs * 8 + cc] = a;
    pss[bs * 8 + cc] = q;
  }
}

// ============ LN1 pass B: normalize + transpose to bf16 [M][C] ============
__global__ __launch_bounds__(256) void k_ln1_norm(const float* __restrict__ x,
    const float* __restrict__ g, const float* __restrict__ bt,
    const float* __restrict__ psum, const float* __restrict__ pss,
    unsigned short* __restrict__ out) {
  int cc = blockIdx.x, st = blockIdx.y, b = blockIdx.z;
  int sl = threadIdx.x & 15, cl = threadIdx.x >> 4;
  int s = st * 16 + sl;
  __shared__ float red[16][17];
  __shared__ float mean_s[16], rstd_s[16];
  int t8 = cl;
  size_t bsrow = (size_t)(b * Sc + st * 16 + sl);
  float v = (t8 < 8) ? psum[bsrow * 8 + t8] : pss[bsrow * 8 + (t8 - 8)];
  red[t8][sl] = v;
  __syncthreads();
  if (threadIdx.x < 16) {
    float s0 = 0.f, s1 = 0.f;
#pragma unroll
    for (int i = 0; i < 8; i++) { s0 += red[i][threadIdx.x]; s1 += red[i + 8][threadIdx.x]; }
    float mean = s0 / Cc;
    mean_s[threadIdx.x] = mean;
    rstd_s[threadIdx.x] = rsqrtf(s1 / Cc - mean * mean + 1e-5f);
  }
  __syncthreads();
  float mean = mean_s[sl], rstd = rstd_s[sl];
  const float* xb = x + (size_t)b * Cc * Sc + s;
  __shared__ unsigned short Tc[16][136];
  int cb = cc * 128;
#pragma unroll
  for (int t = 0; t < 8; t++) {
    int c = cb + cl + t * 16;
    float xv = xb[(size_t)c * Sc];
    Tc[sl][cl + t * 16] = f2bf((xv - mean) * rstd * g[c] + bt[c]);
  }
  __syncthreads();
  int rl = threadIdx.x >> 4, el = threadIdx.x & 15;
  unsigned short* ob = out + ((size_t)(b * Sc) + st * 16 + rl) * Cc + cb;
  *(u16x8*)&ob[el * 8] = *(const u16x8*)&Tc[rl][el * 8];
}

// ============ bf16 MFMA GEMM, 512 thr = 8 waves (2Mx4N), reg-staged double-buffer ============
// C[M][N] = A[M][K] @ Bt[N][K]^T. EPI: 0 none,1 +bias,2 +bias+res,3 +bias+gelu. OUTM bit0 f32, bit1 bf16.
template<int EPI, int OUTM>
__global__ __launch_bounds__(512) void gemm_bf16(
    const unsigned short* __restrict__ A, const unsigned short* __restrict__ Bt,
    const float* __restrict__ bias, const float* __restrict__ res,
    float* __restrict__ Cf, unsigned short* __restrict__ Cb,
    int M, int N, int K) {
  __shared__ unsigned short As[128][72];
  __shared__ unsigned short Bs[128][72];
  int tid = threadIdx.x;
  int w = tid >> 6, lane = tid & 63, g = lane >> 4, l16 = lane & 15;
  int wm = w >> 2, wn = w & 3;             // 2 x 4 waves; wave tile 64M x 32N
  int m0 = blockIdx.y * 128, n0 = blockIdx.x * 128;
  int r0 = tid >> 3, ch0 = (tid & 7) * 8;          // staging slot 0 (rows 0..63)
  int r1 = r0 + 64;                                 // staging slot 1 (rows 64..127)
  const unsigned short* Arow0 = A + (size_t)(m0 + r0) * K + ch0;
  const unsigned short* Arow1 = A + (size_t)(m0 + r1) * K + ch0;
  const unsigned short* Brow0 = Bt + (size_t)(n0 + r0) * K + ch0;
  const unsigned short* Brow1 = Bt + (size_t)(n0 + r1) * K + ch0;
  u16x8 ra0 = *(const u16x8*)Arow0;
  u16x8 ra1 = *(const u16x8*)Arow1;
  u16x8 rb0 = *(const u16x8*)Brow0;
  u16x8 rb1 = *(const u16x8*)Brow1;
  f32x4 acc[4][2] = {};
  for (int k0 = 0; k0 < K; k0 += 64) {
    __syncthreads();
    *(u16x8*)&As[r0][ch0] = ra0;
    *(u16x8*)&As[r1][ch0] = ra1;
    *(u16x8*)&Bs[r0][ch0] = rb0;
    *(u16x8*)&Bs[r1][ch0] = rb1;
    __syncthreads();
    if (k0 + 64 < K) {                       // issue next-tile loads; hide under MFMA
      ra0 = *(const u16x8*)(Arow0 + k0 + 64);
      ra1 = *(const u16x8*)(Arow1 + k0 + 64);
      rb0 = *(const u16x8*)(Brow0 + k0 + 64);
      rb1 = *(const u16x8*)(Brow1 + k0 + 64);
    }
#pragma unroll
    for (int ks = 0; ks < 2; ks++) {
      short8_t af[4], bf[2];
#pragma unroll
      for (int i = 0; i < 4; i++)
        af[i] = *(const short8_t*)&As[wm * 64 + i * 16 + l16][ks * 32 + g * 8];
#pragma unroll
      for (int j = 0; j < 2; j++)
        bf[j] = *(const short8_t*)&Bs[wn * 32 + j * 16 + l16][ks * 32 + g * 8];
#pragma unroll
      for (int mi = 0; mi < 4; mi++)
#pragma unroll
        for (int ni = 0; ni < 2; ni++)
          acc[mi][ni] = __builtin_amdgcn_mfma_f32_16x16x32_bf16(af[mi], bf[ni], acc[mi][ni], 0, 0, 0);
    }
  }
#pragma unroll
  for (int mi = 0; mi < 4; mi++) {
#pragma unroll
    for (int ni = 0; ni < 2; ni++) {
      int n = n0 + wn * 32 + ni * 16 + l16;
      float bv = 0.f;
      if (EPI != 0) bv = bias[n];
#pragma unroll
      for (int r = 0; r < 4; r++) {
        int m = m0 + wm * 64 + mi * 16 + g * 4 + r;
        float c = acc[mi][ni][r] + bv;
        if (EPI == 2) c += res[(size_t)m * N + n];
        if (EPI == 3) c = 0.5f * c * (1.f + erff(c * 0.70710678118f));
        if (OUTM & 1) Cf[(size_t)m * N + n] = c;
        if (OUTM & 2) Cb[(size_t)m * N + n] = f2bf(c);
      }
    }
  }
}

// ============ MHSA: MFMA bf16 flash, double-buffered K/V staging, V via tr-read ============
__global__ __launch_bounds__(256) void k_attn_mfma(const unsigned short* __restrict__ qkv,
    unsigned short* __restrict__ o) {
  __shared__ unsigned short Ks[64][72];     // [key][dh]
  __shared__ unsigned short Vs[4608];       // subtiled, dd-stride 72, kk-stride 288
  __shared__ unsigned short Plb[4][16][72]; // per-wave P (bf16, A-frag-ready rows)
  int qt = blockIdx.x, h = blockIdx.y, b = blockIdx.z;
  int tid = threadIdx.x;
  int w = tid >> 6, lane = tid & 63;
  int g = lane >> 4, l16 = lane & 15;
  const unsigned short* base  = qkv + (size_t)b * Sc * E3;
  const unsigned short* kbase = base + Ec + h * 64;
  const unsigned short* vbase = base + 2 * Ec + h * 64;
  int q0 = qt * 64 + w * 16;

  // Q frags, pre-scaled by exact pow2 1/sqrt(64)
  short8_t qf[2];
#pragma unroll
  for (int ks = 0; ks < 2; ks++) {
    short8_t f = *(const short8_t*)&base[(size_t)(q0 + l16) * E3 + h * 64 + ks * 32 + g * 8];
#pragma unroll
    for (int e = 0; e < 8; e++)
      f[e] = (short)f2bf(bf2f((unsigned short)f[e]) * 0.125f);
    qf[ks] = f;
  }

  // staging geometry (2 slots x 16B per thread)
  int r0s = tid >> 3, ch0s = (tid & 7) * 8;
  int r1s = ((tid + 256) >> 3), ch1s = ch0s;        // rows 32..63
  int voff0 = (r0s >> 2) * 288 + (ch0s >> 4) * 72 + (r0s & 3) * 16 + ((ch0s >> 3) & 1) * 8;
  int voff1 = (r1s >> 2) * 288 + (ch1s >> 4) * 72 + (r1s & 3) * 16 + ((ch1s >> 3) & 1) * 8;
  const unsigned short* krow0 = kbase + (size_t)r0s * E3 + ch0s;
  const unsigned short* krow1 = kbase + (size_t)r1s * E3 + ch1s;
  const unsigned short* vrow0 = vbase + (size_t)r0s * E3 + ch0s;
  const unsigned short* vrow1 = vbase + (size_t)r1s * E3 + ch1s;
  constexpr size_t KTS = (size_t)64 * E3;           // elements per 64-key step

  u16x8 rk0 = *(const u16x8*)krow0;
  u16x8 rk1 = *(const u16x8*)krow1;
  u16x8 rv0 = *(const u16x8*)vrow0;
  u16x8 rv1 = *(const u16x8*)vrow1;

  f32x4 o_acc[4] = {};
  float m_r[4] = {-1e30f, -1e30f, -1e30f, -1e30f};
  float l_r[4] = {};

  for (int kt = 0; kt < 16; kt++) {
    __syncthreads();
    *(u16x8*)&Ks[r0s][ch0s] = rk0;
    *(u16x8*)&Ks[r1s][ch1s] = rk1;
    *(u16x8*)&Vs[voff0] = rv0;
    *(u16x8*)&Vs[voff1] = rv1;
    __syncthreads();
    if (kt < 15) {                                   // issue kt+1 loads; hide under compute
      size_t off = (size_t)(kt + 1) * KTS;
      rk0 = *(const u16x8*)(krow0 + off);
      rk1 = *(const u16x8*)(krow1 + off);
      rv0 = *(const u16x8*)(vrow0 + off);
      rv1 = *(const u16x8*)(vrow1 + off);
    }

    // S = Q @ K^T
    f32x4 s_acc[4] = {};
#pragma unroll
    for (int nt = 0; nt < 4; nt++) {
#pragma unroll
      for (int ks = 0; ks < 2; ks++) {
        short8_t kf = *(const short8_t*)&Ks[nt * 16 + l16][ks * 32 + g * 8];
        s_acc[nt] = __builtin_amdgcn_mfma_f32_16x16x32_bf16(qf[ks], kf, s_acc[nt], 0, 0, 0);
      }
    }

    // online softmax; C-layout row=(g*4+r), col=l16+16*nt
#pragma unroll
    for (int r = 0; r < 4; r++) {
      float mx = fmaxf(fmaxf(s_acc[0][r], s_acc[1][r]), fmaxf(s_acc[2][r], s_acc[3][r]));
#pragma unroll
      for (int off = 8; off; off >>= 1) mx = fmaxf(mx, __shfl_xor(mx, off));
      float mn = fmaxf(m_r[r], mx);
      float sc = __expf(m_r[r] - mn);
      m_r[r] = mn;
      l_r[r] *= sc;
#pragma unroll
      for (int dt = 0; dt < 4; dt++) o_acc[dt][r] *= sc;
      float ts = 0.f;
#pragma unroll
      for (int nt = 0; nt < 4; nt++) {
        float p = __expf(s_acc[nt][r] - mn);
        s_acc[nt][r] = p;
        ts += p;
      }
#pragma unroll
      for (int off = 8; off; off >>= 1) ts += __shfl_xor(ts, off);
      l_r[r] += ts;
    }

    // P (C-layout) -> bf16 LDS rows (software RNE: avoid biased truncation)
#pragma unroll
    for (int nt = 0; nt < 4; nt++)
#pragma unroll
      for (int r = 0; r < 4; r++)
        Plb[w][g * 4 + r][nt * 16 + l16] = f2bf(s_acc[nt][r]);

#pragma unroll
    for (int ks = 0; ks < 2; ks++) {
      short8_t pf = *(const short8_t*)&Plb[w][l16][ks * 32 + g * 8];
      short4_t lo0, lo1, lo2, lo3, hi0, hi1, hi2, hi3;
      unsigned a0 = (unsigned)(uintptr_t)&Vs[(ks * 8 + g * 2) * 288 + 0 * 72 + l16] * 1u;
      unsigned a1 = a0 + 144, a2 = a0 + 288, a3 = a0 + 432;
      asm volatile("ds_read_b64_tr_b16 %0, %1" : "=v"(lo0) : "v"(a0));
      asm volatile("ds_read_b64_tr_b16 %0, %1 offset:576" : "=v"(hi0) : "v"(a0));
      asm volatile("ds_read_b64_tr_b16 %0, %1" : "=v"(lo1) : "v"(a1));
      asm volatile("ds_read_b64_tr_b16 %0, %1 offset:576" : "=v"(hi1) : "v"(a1));
      asm volatile("ds_read_b64_tr_b16 %0, %1" : "=v"(lo2) : "v"(a2));
      asm volatile("ds_read_b64_tr_b16 %0, %1 offset:576" : "=v"(hi2) : "v"(a2));
      asm volatile("ds_read_b64_tr_b16 %0, %1" : "=v"(lo3) : "v"(a3));
      asm volatile("ds_read_b64_tr_b16 %0, %1 offset:576" : "=v"(hi3) : "v"(a3));
      asm volatile("s_waitcnt lgkmcnt(0)");
      __builtin_amdgcn_sched_barrier(0);
      short4_t lo[4] = {lo0, lo1, lo2, lo3};
      short4_t hi[4] = {hi0, hi1, hi2, hi3};
#pragma unroll
      for (int dt = 0; dt < 4; dt++) {
        short8_t vf;
#pragma unroll
        for (int e = 0; e < 4; e++) { vf[e] = lo[dt][e]; vf[4 + e] = hi[dt][e]; }
        o_acc[dt] = __builtin_amdgcn_mfma_f32_16x16x32_bf16(pf, vf, o_acc[dt], 0, 0, 0);
      }
    }
  }

  unsigned short* obase = o + (size_t)(b * Sc + q0) * Ec + h * 64;
#pragma unroll
  for (int r = 0; r < 4; r++) {
    float inv = 1.f / l_r[r];
    int qrow = g * 4 + r;
#pragma unroll
    for (int dt = 0; dt < 4; dt++)
      obase[(size_t)qrow * Ec + dt * 16 + l16] = f2bf(o_acc[dt][r] * inv);
  }
}

// ============ LN over rows of E=768 (row-major outs) ============
template<int MODE>
__global__ __launch_bounds__(256) void k_lnrow(const float* __restrict__ in,
    const float* __restrict__ g, const float* __restrict__ bt,
    float* __restrict__ outf, unsigned short* __restrict__ outb) {
  int row = blockIdx.x;
  int tid = threadIdx.x;
  __shared__ float buf[Ec];
  __shared__ float rsum[4], rss[4];
  float sum = 0.f, ss = 0.f;
  for (int i = tid; i < Ec; i += 256) {
    float v = in[(size_t)row * Ec + i];
    buf[i] = v; sum += v; ss += v * v;
  }
#pragma unroll
  for (int off = 32; off > 0; off >>= 1) {
    sum += __shfl_xor(sum, off); ss += __shfl_xor(ss, off);
  }
  if ((tid & 63) == 0) { rsum[tid >> 6] = sum; rss[tid >> 6] = ss; }
  __syncthreads();
  sum = rsum[0] + rsum[1] + rsum[2] + rsum[3];
  ss = rss[0] + rss[1] + rss[2] + rss[3];
  float mean = sum / Ec;
  float rstd = rsqrtf(ss / Ec - mean * mean + 1e-5f);
  for (int i = tid; i < Ec; i += 256) {
    float v = (buf[i] - mean) * rstd * g[i] + bt[i];
    if (MODE == 2) outf[(size_t)row * Ec + i] = v;
    outb[(size_t)row * Ec + i] = f2bf(v);
  }
}

// ============ final LN: out = LN(n3+mlp) transposed to [B,E,H,W] ============
__global__ __launch_bounds__(256) void k_lnout(const float* __restrict__ in,
    const float* __restrict__ res, const float* __restrict__ g,
    const float* __restrict__ bt, float* __restrict__ out) {
  int r0 = blockIdx.x * 16;
  int b = r0 >> 10, s0 = r0 & 1023;
  __shared__ float Tr[16][772];
  __shared__ float mean_s[16], rstd_s[16];
  int rl = threadIdx.x >> 4, el = threadIdx.x & 15;
  const float* ip = in + (size_t)(r0 + rl) * Ec;
  const float* rp = res + (size_t)(r0 + rl) * Ec;
  float sum = 0.f, ss = 0.f;
  for (int i = el; i < Ec; i += 16) {
    float v = ip[i] + rp[i];
    Tr[rl][i] = v; sum += v; ss += v * v;
  }
#pragma unroll
  for (int off = 8; off; off >>= 1) {
    sum += __shfl_xor(sum, off); ss += __shfl_xor(ss, off);
  }
  if (el == 0) {
    float mean = sum / Ec;
    mean_s[rl] = mean;
    rstd_s[rl] = rsqrtf(ss / Ec - mean * mean + 1e-5f);
  }
  __syncthreads();
  int sl = threadIdx.x & 15, il = threadIdx.x >> 4;
  float mean = mean_s[sl], rstd = rstd_s[sl];
  for (int i = il; i < Ec; i += 16)
    out[((size_t)b * Ec + i) * Sc + s0 + sl] = (Tr[sl][i] - mean) * rstd * g[i] + bt[i];
}

// ============ per-node attention coefficients a_s, a_d ============
__global__ __launch_bounds__(256) void k_asd(const float* __restrict__ hN,
    const float* __restrict__ att_src, const float* __restrict__ att_dst,
    float* __restrict__ a_s, float* __restrict__ a_d) {
  int n = blockIdx.x * 4 + (threadIdx.x >> 6);
  int lane = threadIdx.x & 63;
  const float* hrow = hN + (size_t)n * Ec;
#pragma unroll
  for (int h = 0; h < GHEAD; h++) {
    float ps = 0.f, pd = 0.f;
    for (int d = lane; d < DGAT; d += 64) {
      float v = hrow[h * DGAT + d];
      ps += v * att_src[h * DGAT + d];
      pd += v * att_dst[h * DGAT + d];
    }
#pragma unroll
    for (int off = 32; off > 0; off >>= 1) {
      ps += __shfl_xor(ps, off); pd += __shfl_xor(pd, off);
    }
    if (lane == 0) { a_s[n * GHEAD + h] = ps; a_d[n * GHEAD + h] = pd; }
  }
}

// ============ GAT stencil ============
__global__ __launch_bounds__(256) void k_gat(const float* __restrict__ hN,
    const float* __restrict__ a_s, const float* __restrict__ a_d,
    const float* __restrict__ x_attn, const float* __restrict__ gat_b,
    float* __restrict__ x_after) {
  int n = blockIdx.x;
  int b = n >> 10, s = n & 1023, r = s >> 5, c = s & 31;
  __shared__ int nbr[9];
  __shared__ float alpha[GHEAD][9];
  int tid = threadIdx.x;
  if (tid < 9) {
    int dr = tid / 3 - 1, dc = tid % 3 - 1;
    int rr = r + dr, cc = c + dc;
    int ok = (rr >= 0 && rr < 32 && cc >= 0 && cc < 32);
    if (dr == -1 && dc == 1 && cc == 31) ok = 0;
    if (dr == 1 && dc == -1 && c == 31) ok = 0;
    nbr[tid] = ok ? ((b << 10) + (rr << 5) + cc) : -1;
  }
  __syncthreads();
  if (tid < GHEAD) {
    int h = tid;
    float ad = a_d[n * GHEAD + h];
    float ev[9]; float m = -1e30f;
#pragma unroll
    for (int j = 0; j < 9; j++) {
      if (nbr[j] >= 0) {
        float e = a_s[nbr[j] * GHEAD + h] + ad;
        e = e > 0.f ? e : 0.2f * e;
        ev[j] = e; m = fmaxf(m, e);
      } else ev[j] = -1e30f;
    }
    float den = 0.f;
#pragma unroll
    for (int j = 0; j < 9; j++) {
      float x = (nbr[j] >= 0) ? expf(ev[j] - m) : 0.f;
      ev[j] = x; den += x;
    }
    float inv = 1.f / den;
#pragma unroll
    for (int j = 0; j < 9; j++) alpha[h][j] = ev[j] * inv;
  }
  __syncthreads();
  for (int e = tid; e < Ec; e += 256) {
    int h = e / DGAT;
    float acc = 0.f;
#pragma unroll
    for (int j = 0; j < 9; j++) {
      int nj = nbr[j];
      if (nj >= 0) acc += alpha[h][j] * hN[(size_t)nj * Ec + e];
    }
    float v = acc + gat_b[e];
    v = v > 0.f ? v : expf(v) - 1.f;
    x_after[(size_t)n * Ec + e] = x_attn[(size_t)n * Ec + e] + v;
  }
}

extern "C" void kernel_launch(void* const* d_in, const int* in_sizes, int n_in,
                              void* d_out, int out_size, void* d_ws, size_t ws_size,
                              hipStream_t stream) {
  (void)in_sizes; (void)n_in; (void)out_size; (void)ws_size;
  const float* x      = (const float*)d_in[0];
  const float* ln1_g  = (const float*)d_in[1];
  const float* ln1_b  = (const float*)d_in[2];
  const float* proj_w = (const float*)d_in[3];
  const float* proj_b = (const float*)d_in[4];
  const float* wqkv   = (const float*)d_in[5];
  const float* bqkv   = (const float*)d_in[6];
  const float* wo     = (const float*)d_in[7];
  const float* bo     = (const float*)d_in[8];
  const float* ln2_g  = (const float*)d_in[9];
  const float* ln2_b  = (const float*)d_in[10];
  const float* gp_w   = (const float*)d_in[11];
  const float* gp_b   = (const float*)d_in[12];
  const float* gat_w  = (const float*)d_in[13];
  const float* att_src= (const float*)d_in[14];
  const float* att_dst= (const float*)d_in[15];
  const float* gat_b  = (const float*)d_in[16];
  const float* ln3_g  = (const float*)d_in[17];
  const float* ln3_b  = (const float*)d_in[18];
  const float* mlp_w1 = (const float*)d_in[19];
  const float* mlp_b1 = (const float*)d_in[20];
  const float* mlp_w2 = (const float*)d_in[21];
  const float* mlp_b2 = (const float*)d_in[22];
  const float* fn_g   = (const float*)d_in[23];
  const float* fn_b   = (const float*)d_in[24];
  float* out = (float*)d_out;

  // ---- workspace layout ----
  char* p = (char*)d_ws;
  auto alloc = [&](size_t bytes) { char* q = p; p += (bytes + 255) & ~(size_t)255; return q; };
  char* regA      = alloc((size_t)Ntok * E3 * 2);            // n1_bf -> qkv_bf
  unsigned short* n1_bf  = (unsigned short*)regA;
  unsigned short* qkv_bf = (unsigned short*)regA;
  unsigned short* proj_wt = (unsigned short*)alloc((size_t)Ec * Cc * 2);
  unsigned short* wqkv_t  = (unsigned short*)alloc((size_t)E3 * Ec * 2);
  unsigned short* wo_t    = (unsigned short*)alloc((size_t)Ec * Ec * 2);
  unsigned short* gp_t    = (unsigned short*)alloc((size_t)Ec * Ec * 2);
  unsigned short* gat_t   = (unsigned short*)alloc((size_t)Ec * Ec * 2);
  unsigned short* m1_t    = (unsigned short*)alloc((size_t)Ec * Ec * 2);
  unsigned short* m2_t    = (unsigned short*)alloc((size_t)Ec * Ec * 2);
  float* v_in   = (float*)alloc((size_t)Ntok * Ec * 4);
  unsigned short* v_in_bf = (unsigned short*)alloc((size_t)Ntok * Ec * 2);
  unsigned short* regE    = (unsigned short*)alloc((size_t)Ntok * Ec * 2); // o_bf -> h1_bf
  float* regF   = (float*)alloc((size_t)Ntok * Ec * 4);      // x_attn -> n3 f32
  unsigned short* regG    = (unsigned short*)alloc((size_t)Ntok * Ec * 2); // n2_bf -> n3_bf
  unsigned short* g_bf    = (unsigned short*)alloc((size_t)Ntok * Ec * 2);
  float* hN     = (float*)alloc((size_t)Ntok * Ec * 4);
  float* regJ   = (float*)alloc((size_t)Ntok * Ec * 4);      // x_after -> mlp_out
  float* a_s    = (float*)alloc((size_t)Ntok * GHEAD * 4);
  float* a_d    = (float*)alloc((size_t)Ntok * GHEAD * 4);
  float* psum   = (float*)alloc((size_t)Ntok * 8 * 4);
  float* pss    = (float*)alloc((size_t)Ntok * 8 * 4);

  unsigned short* o_bf   = regE;
  unsigned short* h1_bf  = regE;
  float* x_attn = regF;
  float* n3_f   = regF;
  unsigned short* n2_bf  = regG;
  unsigned short* n3_bf  = regG;
  float* x_after = regJ;
  float* mlp_out = regJ;

  // 0) weights -> transposed bf16
  WtArgs wa;
  wa.src[0] = proj_w; wa.dst[0] = proj_wt; wa.K[0] = Cc; wa.N[0] = Ec;
  wa.src[1] = wqkv;   wa.dst[1] = wqkv_t;  wa.K[1] = Ec; wa.N[1] = E3;
  wa.src[2] = wo;     wa.dst[2] = wo_t;    wa.K[2] = Ec; wa.N[2] = Ec;
  wa.src[3] = gp_w;   wa.dst[3] = gp_t;    wa.K[3] = Ec; wa.N[3] = Ec;
  wa.src[4] = gat_w;  wa.dst[4] = gat_t;   wa.K[4] = Ec; wa.N[4] = Ec;
  wa.src[5] = mlp_w1; wa.dst[5] = m1_t;    wa.K[5] = Ec; wa.N[5] = Ec;
  wa.src[6] = mlp_w2; wa.dst[6] = m2_t;    wa.K[6] = Ec; wa.N[6] = Ec;
  int cum = 0;
  for (int i = 0; i < 7; i++) { wa.off[i] = cum; cum += (wa.K[i] >> 5) * (wa.N[i] >> 5); }
  wa.off[7] = cum;
  k_wt<<<cum, 256, 0, stream>>>(wa);

  // 1) LN1 two-pass -> bf16 [M][C]
  k_ln1_stats<<<dim3(8, 64, 4), 256, 0, stream>>>(x, psum, pss);
  k_ln1_norm<<<dim3(16, 64, 4), 256, 0, stream>>>(x, ln1_g, ln1_b, psum, pss, n1_bf);
  // 2) v_in = n1 @ proj_w + proj_b  (f32 + bf16 out)
  gemm_bf16<1, 3><<<dim3(Ec / 128, Ntok / 128), 512, 0, stream>>>(
      n1_bf, proj_wt, proj_b, nullptr, v_in, v_in_bf, Ntok, Ec, Cc);
  // 3) qkv = v_in @ wqkv + bqkv  (bf16 out)
  gemm_bf16<1, 2><<<dim3(E3 / 128, Ntok / 128), 512, 0, stream>>>(
      v_in_bf, wqkv_t, bqkv, nullptr, nullptr, qkv_bf, Ntok, E3, Ec);
  // 4) attention
  k_attn_mfma<<<dim3(16, NHEAD, Bc), 256, 0, stream>>>(qkv_bf, o_bf);
  // 5) x_attn = v_in + o @ wo + bo  (f32)
  gemm_bf16<2, 1><<<dim3(Ec / 128, Ntok / 128), 512, 0, stream>>>(
      o_bf, wo_t, bo, v_in, x_attn, nullptr, Ntok, Ec, Ec);
  // 6) n2 = LN(x_attn) -> bf16
  k_lnrow<0><<<Ntok, 256, 0, stream>>>(x_attn, ln2_g, ln2_b, nullptr, n2_bf);
  // 7) g = n2 @ gp_w + gp_b -> bf16
  gemm_bf16<1, 2><<<dim3(Ec / 128, Ntok / 128), 512, 0, stream>>>(
      n2_bf, gp_t, gp_b, nullptr, nullptr, g_bf, Ntok, Ec, Ec);
  // 8) hN = g @ gat_w -> f32
  gemm_bf16<0, 1><<<dim3(Ec / 128, Ntok / 128), 512, 0, stream>>>(
      g_bf, gat_t, nullptr, nullptr, hN, nullptr, Ntok, Ec, Ec);
  // 9) a_s, a_d
  k_asd<<<Ntok / 4, 256, 0, stream>>>(hN, att_src, att_dst, a_s, a_d);
  // 10) GAT aggregate + elu + residual -> x_after
  k_gat<<<Ntok, 256, 0, stream>>>(hN, a_s, a_d, x_attn, gat_b, x_after);
  // 11) n3 = LN(x_after) -> f32 + bf16
  k_lnrow<2><<<Ntok, 256, 0, stream>>>(x_after, ln3_g, ln3_b, n3_f, n3_bf);
  // 12) h1 = gelu(n3 @ mlp_w1 + mlp_b1) -> bf16
  gemm_bf16<3, 2><<<dim3(Ec / 128, Ntok / 128), 512, 0, stream>>>(
      n3_bf, m1_t, mlp_b1, nullptr, nullptr, h1_bf, Ntok, Ec, Ec);
  // 13) mlp = h1 @ mlp_w2 + mlp_b2 -> f32
  gemm_bf16<1, 1><<<dim3(Ec / 128, Ntok / 128), 512, 0, stream>>>(
      h1_bf, m2_t, mlp_b2, nullptr, mlp_out, nullptr, Ntok, Ec, Ec);
  // 14) out = LN(n3 + mlp), transposed to [B,E,H,W]
  k_lnout<<<256, 256, 0, stream>>>(n3_f, mlp_out, fn_g, fn_b, out);
}

// Round 7
// 260.533 us; speedup vs baseline: 8.9450x; 1.0193x over previous
//
#include <hip/hip_runtime.h>

// ---- problem constants ----
constexpr int Bc = 4;
constexpr int Cc = 2048;
constexpr int Sc = 1024;     // H*W = 32*32
constexpr int Ntok = 4096;   // B*S
constexpr int Ec = 768;
constexpr int E3 = 2304;
constexpr int NHEAD = 12;
constexpr int GHEAD = 4;
constexpr int DGAT = 192;

typedef __attribute__((ext_vector_type(8))) short short8_t;   // bf16x8 MFMA frag
typedef __attribute__((ext_vector_type(4))) short short4_t;
typedef __attribute__((ext_vector_type(8))) unsigned short u16x8;
typedef __attribute__((ext_vector_type(4))) float f32x4;

// software RNE f32->bf16
__device__ inline unsigned short f2bf(float f) {
  unsigned int u = __builtin_bit_cast(unsigned int, f);
  u += 0x7FFFu + ((u >> 16) & 1u);
  return (unsigned short)(u >> 16);
}
__device__ inline float bf2f(unsigned short h) {
  unsigned int u = ((unsigned int)h) << 16;
  return __builtin_bit_cast(float, u);
}

// ============ weight prep: 6 transposed + 1 identity bf16 cast ============
struct WtArgs {
  const float* src[7];
  unsigned short* dst[7];
  int K[7], N[7], mode[7];   // mode 0: dst[n][k]=src[k][n]; mode 1: dst[k][n]=src[k][n]
  int off[8];
};
__global__ __launch_bounds__(256) void k_wt(WtArgs a) {
  __shared__ float t[32][33];
  int bid = blockIdx.x;
  int w = 0;
  while (w < 6 && bid >= a.off[w + 1]) ++w;
  int local = bid - a.off[w];
  int K = a.K[w], N = a.N[w];
  int ntn = N >> 5;
  int tk = local / ntn, tn = local - tk * ntn;
  int k0 = tk * 32, n0 = tn * 32;
  int tx = threadIdx.x & 31, ty = threadIdx.x >> 5;
  const float* src = a.src[w];
  unsigned short* dst = a.dst[w];
  if (a.mode[w]) {
#pragma unroll
    for (int i = 0; i < 4; i++)
      dst[(size_t)(k0 + ty + i * 8) * N + n0 + tx] =
          f2bf(src[(size_t)(k0 + ty + i * 8) * N + n0 + tx]);
    return;
  }
#pragma unroll
  for (int i = 0; i < 4; i++)
    t[ty + i * 8][tx] = src[(size_t)(k0 + ty + i * 8) * N + n0 + tx];
  __syncthreads();
#pragma unroll
  for (int i = 0; i < 4; i++)
    dst[(size_t)(n0 + ty + i * 8) * K + k0 + tx] = f2bf(t[tx][ty + i * 8]);
}

// ============ bias2 = gp_b @ gat_w (vector-matrix), partials + reduce ============
__global__ __launch_bounds__(256) void k_bias2p(const float* __restrict__ gat_w,
    const float* __restrict__ gp_b, float* __restrict__ part) {
  int m = blockIdx.x * 256 + threadIdx.x;
  int jc = blockIdx.y;
  float acc = 0.f;
#pragma unroll 8
  for (int j = jc * 96; j < jc * 96 + 96; j++)
    acc += gp_b[j] * gat_w[(size_t)j * Ec + m];
  part[jc * Ec + m] = acc;
}
__global__ __launch_bounds__(256) void k_bias2r(const float* __restrict__ part,
    float* __restrict__ bias2) {
  int m = blockIdx.x * 256 + threadIdx.x;
  float acc = 0.f;
#pragma unroll
  for (int j = 0; j < 8; j++) acc += part[j * Ec + m];
  bias2[m] = acc;
}

// ============ LN1 pass A: partial sums over 256-c chunks ============
__global__ __launch_bounds__(256) void k_ln1_stats(const float* __restrict__ x,
    float* __restrict__ psum, float* __restrict__ pss) {
  int cc = blockIdx.x, st = blockIdx.y, b = blockIdx.z;
  int sl = threadIdx.x & 15, cl = threadIdx.x >> 4;
  int s = st * 16 + sl;
  const float* xb = x + (size_t)b * Cc * Sc + s;
  float sum = 0.f, ss = 0.f;
#pragma unroll
  for (int t = 0; t < 16; t++) {
    int c = cc * 256 + cl + t * 16;
    float v = xb[(size_t)c * Sc];
    sum += v; ss += v * v;
  }
  __shared__ float rs0[16][17], rs1[16][17];
  rs0[cl][sl] = sum; rs1[cl][sl] = ss;
  __syncthreads();
  if (cl == 0) {
    float a = 0.f, q = 0.f;
#pragma unroll
    for (int i = 0; i < 16; i++) { a += rs0[i][sl]; q += rs1[i][sl]; }
    size_t bs = (size_t)(b * Sc + st * 16 + sl);
    psum[bs * 8 + cc] = a;
    pss[bs * 8 + cc] = q;
  }
}

// ============ LN1 pass B: normalize + transpose to bf16 [M][C] ============
__global__ __launch_bounds__(256) void k_ln1_norm(const float* __restrict__ x,
    const float* __restrict__ g, const float* __restrict__ bt,
    const float* __restrict__ psum, const float* __restrict__ pss,
    unsigned short* __restrict__ out) {
  int cc = blockIdx.x, st = blockIdx.y, b = blockIdx.z;
  int sl = threadIdx.x & 15, cl = threadIdx.x >> 4;
  int s = st * 16 + sl;
  __shared__ float red[16][17];
  __shared__ float mean_s[16], rstd_s[16];
  int t8 = cl;
  size_t bsrow = (size_t)(b * Sc + st * 16 + sl);
  float v = (t8 < 8) ? psum[bsrow * 8 + t8] : pss[bsrow * 8 + (t8 - 8)];
  red[t8][sl] = v;
  __syncthreads();
  if (threadIdx.x < 16) {
    float s0 = 0.f, s1 = 0.f;
#pragma unroll
    for (int i = 0; i < 8; i++) { s0 += red[i][threadIdx.x]; s1 += red[i + 8][threadIdx.x]; }
    float mean = s0 / Cc;
    mean_s[threadIdx.x] = mean;
    rstd_s[threadIdx.x] = rsqrtf(s1 / Cc - mean * mean + 1e-5f);
  }
  __syncthreads();
  float mean = mean_s[sl], rstd = rstd_s[sl];
  const float* xb = x + (size_t)b * Cc * Sc + s;
  __shared__ unsigned short Tc[16][136];
  int cb = cc * 128;
#pragma unroll
  for (int t = 0; t < 8; t++) {
    int c = cb + cl + t * 16;
    float xv = xb[(size_t)c * Sc];
    Tc[sl][cl + t * 16] = f2bf((xv - mean) * rstd * g[c] + bt[c]);
  }
  __syncthreads();
  int rl = threadIdx.x >> 4, el = threadIdx.x & 15;
  unsigned short* ob = out + ((size_t)(b * Sc) + st * 16 + rl) * Cc + cb;
  *(u16x8*)&ob[el * 8] = *(const u16x8*)&Tc[rl][el * 8];
}

// ============ bf16 MFMA GEMM, 512 thr = 8 waves (2Mx4N), reg-staged double-buffer ============
template<int EPI, int OUTM>
__global__ __launch_bounds__(512) void gemm_bf16(
    const unsigned short* __restrict__ A, const unsigned short* __restrict__ Bt,
    const float* __restrict__ bias, const float* __restrict__ res,
    float* __restrict__ Cf, unsigned short* __restrict__ Cb,
    int M, int N, int K) {
  __shared__ unsigned short As[128][72];
  __shared__ unsigned short Bs[128][72];
  int tid = threadIdx.x;
  int w = tid >> 6, lane = tid & 63, g = lane >> 4, l16 = lane & 15;
  int wm = w >> 2, wn = w & 3;
  int m0 = blockIdx.y * 128, n0 = blockIdx.x * 128;
  int r0 = tid >> 3, ch0 = (tid & 7) * 8;
  int r1 = r0 + 64;
  const unsigned short* Arow0 = A + (size_t)(m0 + r0) * K + ch0;
  const unsigned short* Arow1 = A + (size_t)(m0 + r1) * K + ch0;
  const unsigned short* Brow0 = Bt + (size_t)(n0 + r0) * K + ch0;
  const unsigned short* Brow1 = Bt + (size_t)(n0 + r1) * K + ch0;
  u16x8 ra0 = *(const u16x8*)Arow0;
  u16x8 ra1 = *(const u16x8*)Arow1;
  u16x8 rb0 = *(const u16x8*)Brow0;
  u16x8 rb1 = *(const u16x8*)Brow1;
  f32x4 acc[4][2] = {};
  for (int k0 = 0; k0 < K; k0 += 64) {
    __syncthreads();
    *(u16x8*)&As[r0][ch0] = ra0;
    *(u16x8*)&As[r1][ch0] = ra1;
    *(u16x8*)&Bs[r0][ch0] = rb0;
    *(u16x8*)&Bs[r1][ch0] = rb1;
    __syncthreads();
    if (k0 + 64 < K) {
      ra0 = *(const u16x8*)(Arow0 + k0 + 64);
      ra1 = *(const u16x8*)(Arow1 + k0 + 64);
      rb0 = *(const u16x8*)(Brow0 + k0 + 64);
      rb1 = *(const u16x8*)(Brow1 + k0 + 64);
    }
#pragma unroll
    for (int ks = 0; ks < 2; ks++) {
      short8_t af[4], bf[2];
#pragma unroll
      for (int i = 0; i < 4; i++)
        af[i] = *(const short8_t*)&As[wm * 64 + i * 16 + l16][ks * 32 + g * 8];
#pragma unroll
      for (int j = 0; j < 2; j++)
        bf[j] = *(const short8_t*)&Bs[wn * 32 + j * 16 + l16][ks * 32 + g * 8];
#pragma unroll
      for (int mi = 0; mi < 4; mi++)
#pragma unroll
        for (int ni = 0; ni < 2; ni++)
          acc[mi][ni] = __builtin_amdgcn_mfma_f32_16x16x32_bf16(af[mi], bf[ni], acc[mi][ni], 0, 0, 0);
    }
  }
#pragma unroll
  for (int mi = 0; mi < 4; mi++) {
#pragma unroll
    for (int ni = 0; ni < 2; ni++) {
      int n = n0 + wn * 32 + ni * 16 + l16;
      float bv = 0.f;
      if (EPI != 0) bv = bias[n];
#pragma unroll
      for (int r = 0; r < 4; r++) {
        int m = m0 + wm * 64 + mi * 16 + g * 4 + r;
        float c = acc[mi][ni][r] + bv;
        if (EPI == 2) c += res[(size_t)m * N + n];
        if (EPI == 3) c = 0.5f * c * (1.f + erff(c * 0.70710678118f));
        if (OUTM & 1) Cf[(size_t)m * N + n] = c;
        if (OUTM & 2) Cb[(size_t)m * N + n] = f2bf(c);
      }
    }
  }
}

// ============ MHSA: swapped-QK MFMA flash (S^T), dbuf staging, V via tr-read ============
__global__ __launch_bounds__(256) void k_attn_mfma(const unsigned short* __restrict__ qkv,
    unsigned short* __restrict__ o) {
  __shared__ unsigned short Ks[64][72];     // [key][dh]
  __shared__ unsigned short Vs[4608];       // subtiled, dd-stride 72, kk-stride 288
  __shared__ unsigned short Plb[4][16][72]; // per-wave P rows [q][k]
  int qt = blockIdx.x, h = blockIdx.y, b = blockIdx.z;
  int tid = threadIdx.x;
  int w = tid >> 6, lane = tid & 63;
  int g = lane >> 4, l16 = lane & 15;
  const unsigned short* base  = qkv + (size_t)b * Sc * E3;
  const unsigned short* kbase = base + Ec + h * 64;
  const unsigned short* vbase = base + 2 * Ec + h * 64;
  int q0 = qt * 64 + w * 16;

  // Q frags (B-operand; same lane->memory mapping as A), pre-scaled by pow2 1/8
  short8_t qf[2];
#pragma unroll
  for (int ks = 0; ks < 2; ks++) {
    short8_t f = *(const short8_t*)&base[(size_t)(q0 + l16) * E3 + h * 64 + ks * 32 + g * 8];
#pragma unroll
    for (int e = 0; e < 8; e++)
      f[e] = (short)f2bf(bf2f((unsigned short)f[e]) * 0.125f);
    qf[ks] = f;
  }

  // staging geometry
  int r0s = tid >> 3, ch0s = (tid & 7) * 8;
  int r1s = r0s + 32;
  int voff0 = (r0s >> 2) * 288 + (ch0s >> 4) * 72 + (r0s & 3) * 16 + ((ch0s >> 3) & 1) * 8;
  int voff1 = (r1s >> 2) * 288 + (ch0s >> 4) * 72 + (r1s & 3) * 16 + ((ch0s >> 3) & 1) * 8;
  const unsigned short* krow0 = kbase + (size_t)r0s * E3 + ch0s;
  const unsigned short* krow1 = kbase + (size_t)r1s * E3 + ch0s;
  const unsigned short* vrow0 = vbase + (size_t)r0s * E3 + ch0s;
  const unsigned short* vrow1 = vbase + (size_t)r1s * E3 + ch0s;
  constexpr size_t KTS = (size_t)64 * E3;

  u16x8 rk0 = *(const u16x8*)krow0;
  u16x8 rk1 = *(const u16x8*)krow1;
  u16x8 rv0 = *(const u16x8*)vrow0;
  u16x8 rv1 = *(const u16x8*)vrow1;

  f32x4 o_acc[4] = {};
  float m_r = -1e30f, l_r = 0.f;    // per-lane state for q-row = l16

  for (int kt = 0; kt < 16; kt++) {
    __syncthreads();
    *(u16x8*)&Ks[r0s][ch0s] = rk0;
    *(u16x8*)&Ks[r1s][ch0s] = rk1;
    *(u16x8*)&Vs[voff0] = rv0;
    *(u16x8*)&Vs[voff1] = rv1;
    __syncthreads();
    if (kt < 15) {
      size_t off = (size_t)(kt + 1) * KTS;
      rk0 = *(const u16x8*)(krow0 + off);
      rk1 = *(const u16x8*)(krow1 + off);
      rv0 = *(const u16x8*)(vrow0 + off);
      rv1 = *(const u16x8*)(vrow1 + off);
    }

    // S^T = K @ Q^T : row = k_local = g*4+r (+16*nt), col = q = l16
    f32x4 s_acc[4] = {};
#pragma unroll
    for (int nt = 0; nt < 4; nt++) {
#pragma unroll
      for (int ks = 0; ks < 2; ks++) {
        short8_t kf = *(const short8_t*)&Ks[nt * 16 + l16][ks * 32 + g * 8];
        s_acc[nt] = __builtin_amdgcn_mfma_f32_16x16x32_bf16(kf, qf[ks], s_acc[nt], 0, 0, 0);
      }
    }

    // softmax for q-row l16: 15 in-lane max + 2 shfl; same for sum
    float mx = s_acc[0][0];
#pragma unroll
    for (int nt = 0; nt < 4; nt++)
#pragma unroll
      for (int r = 0; r < 4; r++) mx = fmaxf(mx, s_acc[nt][r]);
    mx = fmaxf(mx, __shfl_xor(mx, 16));
    mx = fmaxf(mx, __shfl_xor(mx, 32));
    float mn = fmaxf(m_r, mx);
    float sc = __expf(m_r - mn);
    m_r = mn;
    float ts = 0.f;
#pragma unroll
    for (int nt = 0; nt < 4; nt++)
#pragma unroll
      for (int r = 0; r < 4; r++) {
        float pv = __expf(s_acc[nt][r] - mn);
        s_acc[nt][r] = pv;
        ts += pv;
      }
    ts += __shfl_xor(ts, 16);
    ts += __shfl_xor(ts, 32);
    l_r = l_r * sc + ts;

    // rescale O rows (o row q' = g*4+r needs sc from lane q')
    float osc[4];
#pragma unroll
    for (int r = 0; r < 4; r++) osc[r] = __shfl(sc, g * 4 + r);
#pragma unroll
    for (int dt = 0; dt < 4; dt++)
#pragma unroll
      for (int r = 0; r < 4; r++) o_acc[dt][r] *= osc[r];

    // P^T in regs -> Plb[q][k], packed b32 pairs (k = nt*16 + g*4 + {0..3})
#pragma unroll
    for (int nt = 0; nt < 4; nt++) {
#pragma unroll
      for (int rp = 0; rp < 2; rp++) {
        unsigned pk = (unsigned)f2bf(s_acc[nt][rp * 2])
                    | ((unsigned)f2bf(s_acc[nt][rp * 2 + 1]) << 16);
        *(unsigned*)&Plb[w][l16][nt * 16 + g * 4 + rp * 2] = pk;
      }
    }

    // O += P @ V ; A-frag rows = q = l16, contiguous reads
#pragma unroll
    for (int ks = 0; ks < 2; ks++) {
      short8_t pf = *(const short8_t*)&Plb[w][l16][ks * 32 + g * 8];
      short4_t lo0, lo1, lo2, lo3, hi0, hi1, hi2, hi3;
      unsigned a0 = (unsigned)(uintptr_t)&Vs[(ks * 8 + g * 2) * 288 + 0 * 72 + l16] * 1u;
      unsigned a1 = a0 + 144, a2 = a0 + 288, a3 = a0 + 432;
      asm volatile("ds_read_b64_tr_b16 %0, %1" : "=v"(lo0) : "v"(a0));
      asm volatile("ds_read_b64_tr_b16 %0, %1 offset:576" : "=v"(hi0) : "v"(a0));
      asm volatile("ds_read_b64_tr_b16 %0, %1" : "=v"(lo1) : "v"(a1));
      asm volatile("ds_read_b64_tr_b16 %0, %1 offset:576" : "=v"(hi1) : "v"(a1));
      asm volatile("ds_read_b64_tr_b16 %0, %1" : "=v"(lo2) : "v"(a2));
      asm volatile("ds_read_b64_tr_b16 %0, %1 offset:576" : "=v"(hi2) : "v"(a2));
      asm volatile("ds_read_b64_tr_b16 %0, %1" : "=v"(lo3) : "v"(a3));
      asm volatile("ds_read_b64_tr_b16 %0, %1 offset:576" : "=v"(hi3) : "v"(a3));
      asm volatile("s_waitcnt lgkmcnt(0)");
      __builtin_amdgcn_sched_barrier(0);
      short4_t lo[4] = {lo0, lo1, lo2, lo3};
      short4_t hi[4] = {hi0, hi1, hi2, hi3};
#pragma unroll
      for (int dt = 0; dt < 4; dt++) {
        short8_t vf;
#pragma unroll
        for (int e = 0; e < 4; e++) { vf[e] = lo[dt][e]; vf[4 + e] = hi[dt][e]; }
        o_acc[dt] = __builtin_amdgcn_mfma_f32_16x16x32_bf16(pf, vf, o_acc[dt], 0, 0, 0);
      }
    }
  }

  // normalize: row q'=g*4+r uses l from lane q'
  float linv = 1.f / l_r;
  float inv4[4];
#pragma unroll
  for (int r = 0; r < 4; r++) inv4[r] = __shfl(linv, g * 4 + r);
  unsigned short* obase = o + (size_t)(b * Sc + q0) * Ec + h * 64;
#pragma unroll
  for (int r = 0; r < 4; r++) {
    int qrow = g * 4 + r;
#pragma unroll
    for (int dt = 0; dt < 4; dt++)
      obase[(size_t)qrow * Ec + dt * 16 + l16] = f2bf(o_acc[dt][r] * inv4[r]);
  }
}

// ============ LN over rows of E=768 (row-major outs) ============
template<int MODE>
__global__ __launch_bounds__(256) void k_lnrow(const float* __restrict__ in,
    const float* __restrict__ g, const float* __restrict__ bt,
    float* __restrict__ outf, unsigned short* __restrict__ outb) {
  int row = blockIdx.x;
  int tid = threadIdx.x;
  __shared__ float buf[Ec];
  __shared__ float rsum[4], rss[4];
  float sum = 0.f, ss = 0.f;
  for (int i = tid; i < Ec; i += 256) {
    float v = in[(size_t)row * Ec + i];
    buf[i] = v; sum += v; ss += v * v;
  }
#pragma unroll
  for (int off = 32; off > 0; off >>= 1) {
    sum += __shfl_xor(sum, off); ss += __shfl_xor(ss, off);
  }
  if ((tid & 63) == 0) { rsum[tid >> 6] = sum; rss[tid >> 6] = ss; }
  __syncthreads();
  sum = rsum[0] + rsum[1] + rsum[2] + rsum[3];
  ss = rss[0] + rss[1] + rss[2] + rss[3];
  float mean = sum / Ec;
  float rstd = rsqrtf(ss / Ec - mean * mean + 1e-5f);
  for (int i = tid; i < Ec; i += 256) {
    float v = (buf[i] - mean) * rstd * g[i] + bt[i];
    if (MODE == 2) outf[(size_t)row * Ec + i] = v;
    outb[(size_t)row * Ec + i] = f2bf(v);
  }
}

// ============ final LN: out = LN(n3+mlp) transposed to [B,E,H,W] ============
__global__ __launch_bounds__(256) void k_lnout(const float* __restrict__ in,
    const float* __restrict__ res, const float* __restrict__ g,
    const float* __restrict__ bt, float* __restrict__ out) {
  int r0 = blockIdx.x * 16;
  int b = r0 >> 10, s0 = r0 & 1023;
  __shared__ float Tr[16][772];
  __shared__ float mean_s[16], rstd_s[16];
  int rl = threadIdx.x >> 4, el = threadIdx.x & 15;
  const float* ip = in + (size_t)(r0 + rl) * Ec;
  const float* rp = res + (size_t)(r0 + rl) * Ec;
  float sum = 0.f, ss = 0.f;
  for (int i = el; i < Ec; i += 16) {
    float v = ip[i] + rp[i];
    Tr[rl][i] = v; sum += v; ss += v * v;
  }
#pragma unroll
  for (int off = 8; off; off >>= 1) {
    sum += __shfl_xor(sum, off); ss += __shfl_xor(ss, off);
  }
  if (el == 0) {
    float mean = sum / Ec;
    mean_s[rl] = mean;
    rstd_s[rl] = rsqrtf(ss / Ec - mean * mean + 1e-5f);
  }
  __syncthreads();
  int sl = threadIdx.x & 15, il = threadIdx.x >> 4;
  float mean = mean_s[sl], rstd = rstd_s[sl];
  for (int i = il; i < Ec; i += 16)
    out[((size_t)b * Ec + i) * Sc + s0 + sl] = (Tr[sl][i] - mean) * rstd * g[i] + bt[i];
}

// ============ per-node attention coefficients a_s, a_d ============
__global__ __launch_bounds__(256) void k_asd(const float* __restrict__ hN,
    const float* __restrict__ att_src, const float* __restrict__ att_dst,
    float* __restrict__ a_s, float* __restrict__ a_d) {
  int n = blockIdx.x * 4 + (threadIdx.x >> 6);
  int lane = threadIdx.x & 63;
  const float* hrow = hN + (size_t)n * Ec;
#pragma unroll
  for (int h = 0; h < GHEAD; h++) {
    float ps = 0.f, pd = 0.f;
    for (int d = lane; d < DGAT; d += 64) {
      float v = hrow[h * DGAT + d];
      ps += v * att_src[h * DGAT + d];
      pd += v * att_dst[h * DGAT + d];
    }
#pragma unroll
    for (int off = 32; off > 0; off >>= 1) {
      ps += __shfl_xor(ps, off); pd += __shfl_xor(pd, off);
    }
    if (lane == 0) { a_s[n * GHEAD + h] = ps; a_d[n * GHEAD + h] = pd; }
  }
}

// ============ GAT stencil ============
__global__ __launch_bounds__(256) void k_gat(const float* __restrict__ hN,
    const float* __restrict__ a_s, const float* __restrict__ a_d,
    const float* __restrict__ x_attn, const float* __restrict__ gat_b,
    float* __restrict__ x_after) {
  int n = blockIdx.x;
  int b = n >> 10, s = n & 1023, r = s >> 5, c = s & 31;
  __shared__ int nbr[9];
  __shared__ float alpha[GHEAD][9];
  int tid = threadIdx.x;
  if (tid < 9) {
    int dr = tid / 3 - 1, dc = tid % 3 - 1;
    int rr = r + dr, cc = c + dc;
    int ok = (rr >= 0 && rr < 32 && cc >= 0 && cc < 32);
    if (dr == -1 && dc == 1 && cc == 31) ok = 0;
    if (dr == 1 && dc == -1 && c == 31) ok = 0;
    nbr[tid] = ok ? ((b << 10) + (rr << 5) + cc) : -1;
  }
  __syncthreads();
  if (tid < GHEAD) {
    int h = tid;
    float ad = a_d[n * GHEAD + h];
    float ev[9]; float m = -1e30f;
#pragma unroll
    for (int j = 0; j < 9; j++) {
      if (nbr[j] >= 0) {
        float e = a_s[nbr[j] * GHEAD + h] + ad;
        e = e > 0.f ? e : 0.2f * e;
        ev[j] = e; m = fmaxf(m, e);
      } else ev[j] = -1e30f;
    }
    float den = 0.f;
#pragma unroll
    for (int j = 0; j < 9; j++) {
      float x = (nbr[j] >= 0) ? expf(ev[j] - m) : 0.f;
      ev[j] = x; den += x;
    }
    float inv = 1.f / den;
#pragma unroll
    for (int j = 0; j < 9; j++) alpha[h][j] = ev[j] * inv;
  }
  __syncthreads();
  for (int e = tid; e < Ec; e += 256) {
    int h = e / DGAT;
    float acc = 0.f;
#pragma unroll
    for (int j = 0; j < 9; j++) {
      int nj = nbr[j];
      if (nj >= 0) acc += alpha[h][j] * hN[(size_t)nj * Ec + e];
    }
    float v = acc + gat_b[e];
    v = v > 0.f ? v : expf(v) - 1.f;
    x_after[(size_t)n * Ec + e] = x_attn[(size_t)n * Ec + e] + v;
  }
}

extern "C" void kernel_launch(void* const* d_in, const int* in_sizes, int n_in,
                              void* d_out, int out_size, void* d_ws, size_t ws_size,
                              hipStream_t stream) {
  (void)in_sizes; (void)n_in; (void)out_size; (void)ws_size;
  const float* x      = (const float*)d_in[0];
  const float* ln1_g  = (const float*)d_in[1];
  const float* ln1_b  = (const float*)d_in[2];
  const float* proj_w = (const float*)d_in[3];
  const float* proj_b = (const float*)d_in[4];
  const float* wqkv   = (const float*)d_in[5];
  const float* bqkv   = (const float*)d_in[6];
  const float* wo     = (const float*)d_in[7];
  const float* bo     = (const float*)d_in[8];
  const float* ln2_g  = (const float*)d_in[9];
  const float* ln2_b  = (const float*)d_in[10];
  const float* gp_w   = (const float*)d_in[11];
  const float* gp_b   = (const float*)d_in[12];
  const float* gat_w  = (const float*)d_in[13];
  const float* att_src= (const float*)d_in[14];
  const float* att_dst= (const float*)d_in[15];
  const float* gat_b  = (const float*)d_in[16];
  const float* ln3_g  = (const float*)d_in[17];
  const float* ln3_b  = (const float*)d_in[18];
  const float* mlp_w1 = (const float*)d_in[19];
  const float* mlp_b1 = (const float*)d_in[20];
  const float* mlp_w2 = (const float*)d_in[21];
  const float* mlp_b2 = (const float*)d_in[22];
  const float* fn_g   = (const float*)d_in[23];
  const float* fn_b   = (const float*)d_in[24];
  float* out = (float*)d_out;

  // ---- workspace layout ----
  char* p = (char*)d_ws;
  auto alloc = [&](size_t bytes) { char* q = p; p += (bytes + 255) & ~(size_t)255; return q; };
  char* regA      = alloc((size_t)Ntok * E3 * 2);            // n1_bf -> qkv_bf
  unsigned short* n1_bf  = (unsigned short*)regA;
  unsigned short* qkv_bf = (unsigned short*)regA;
  unsigned short* proj_wt = (unsigned short*)alloc((size_t)Ec * Cc * 2);
  unsigned short* wqkv_t  = (unsigned short*)alloc((size_t)E3 * Ec * 2);
  unsigned short* wo_t    = (unsigned short*)alloc((size_t)Ec * Ec * 2);
  unsigned short* gp_bf   = (unsigned short*)alloc((size_t)Ec * Ec * 2);  // identity cast
  unsigned short* gat_t   = (unsigned short*)alloc((size_t)Ec * Ec * 2);
  unsigned short* m1_t    = (unsigned short*)alloc((size_t)Ec * Ec * 2);
  unsigned short* m2_t    = (unsigned short*)alloc((size_t)Ec * Ec * 2);
  unsigned short* gpgat_t = (unsigned short*)alloc((size_t)Ec * Ec * 2);  // (gp_w@gat_w)^T bf16
  float* bias2p = (float*)alloc((size_t)8 * Ec * 4);
  float* bias2  = (float*)alloc((size_t)Ec * 4);
  float* v_in   = (float*)alloc((size_t)Ntok * Ec * 4);
  unsigned short* v_in_bf = (unsigned short*)alloc((size_t)Ntok * Ec * 2);
  unsigned short* regE    = (unsigned short*)alloc((size_t)Ntok * Ec * 2); // o_bf -> h1_bf
  float* regF   = (float*)alloc((size_t)Ntok * Ec * 4);      // x_attn -> n3 f32
  unsigned short* regG    = (unsigned short*)alloc((size_t)Ntok * Ec * 2); // n2_bf -> n3_bf
  float* hN     = (float*)alloc((size_t)Ntok * Ec * 4);
  float* regJ   = (float*)alloc((size_t)Ntok * Ec * 4);      // x_after -> mlp_out
  float* a_s    = (float*)alloc((size_t)Ntok * GHEAD * 4);
  float* a_d    = (float*)alloc((size_t)Ntok * GHEAD * 4);
  float* psum   = (float*)alloc((size_t)Ntok * 8 * 4);
  float* pss    = (float*)alloc((size_t)Ntok * 8 * 4);

  unsigned short* o_bf   = regE;
  unsigned short* h1_bf  = regE;
  float* x_attn = regF;
  float* n3_f   = regF;
  unsigned short* n2_bf  = regG;
  unsigned short* n3_bf  = regG;
  float* x_after = regJ;
  float* mlp_out = regJ;

  // 0) weights -> bf16 (6 transposed + gp identity)
  WtArgs wa;
  wa.src[0] = proj_w; wa.dst[0] = proj_wt; wa.K[0] = Cc; wa.N[0] = Ec;  wa.mode[0] = 0;
  wa.src[1] = wqkv;   wa.dst[1] = wqkv_t;  wa.K[1] = Ec; wa.N[1] = E3;  wa.mode[1] = 0;
  wa.src[2] = wo;     wa.dst[2] = wo_t;    wa.K[2] = Ec; wa.N[2] = Ec;  wa.mode[2] = 0;
  wa.src[3] = gat_w;  wa.dst[3] = gat_t;   wa.K[3] = Ec; wa.N[3] = Ec;  wa.mode[3] = 0;
  wa.src[4] = mlp_w1; wa.dst[4] = m1_t;    wa.K[4] = Ec; wa.N[4] = Ec;  wa.mode[4] = 0;
  wa.src[5] = mlp_w2; wa.dst[5] = m2_t;    wa.K[5] = Ec; wa.N[5] = Ec;  wa.mode[5] = 0;
  wa.src[6] = gp_w;   wa.dst[6] = gp_bf;   wa.K[6] = Ec; wa.N[6] = Ec;  wa.mode[6] = 1;
  int cum = 0;
  for (int i = 0; i < 7; i++) { wa.off[i] = cum; cum += (wa.K[i] >> 5) * (wa.N[i] >> 5); }
  wa.off[7] = cum;
  k_wt<<<cum, 256, 0, stream>>>(wa);

  // 0b) fused gp@gat weight: W't[m][n] = sum_j gat_t[m][j]*gp_bf[n][j]; bias2 = gp_b@gat_w
  k_bias2p<<<dim3(3, 8), 256, 0, stream>>>(gat_w, gp_b, bias2p);
  k_bias2r<<<3, 256, 0, stream>>>(bias2p, bias2);
  gemm_bf16<0, 2><<<dim3(Ec / 128, Ec / 128), 512, 0, stream>>>(
      gat_t, gp_bf, nullptr, nullptr, nullptr, gpgat_t, Ec, Ec, Ec);

  // 1) LN1 two-pass -> bf16 [M][C]
  k_ln1_stats<<<dim3(8, 64, 4), 256, 0, stream>>>(x, psum, pss);
  k_ln1_norm<<<dim3(16, 64, 4), 256, 0, stream>>>(x, ln1_g, ln1_b, psum, pss, n1_bf);
  // 2) v_in = n1 @ proj_w + proj_b  (f32 + bf16 out)
  gemm_bf16<1, 3><<<dim3(Ec / 128, Ntok / 128), 512, 0, stream>>>(
      n1_bf, proj_wt, proj_b, nullptr, v_in, v_in_bf, Ntok, Ec, Cc);
  // 3) qkv = v_in @ wqkv + bqkv  (bf16 out)
  gemm_bf16<1, 2><<<dim3(E3 / 128, Ntok / 128), 512, 0, stream>>>(
      v_in_bf, wqkv_t, bqkv, nullptr, nullptr, qkv_bf, Ntok, E3, Ec);
  // 4) attention
  k_attn_mfma<<<dim3(16, NHEAD, Bc), 256, 0, stream>>>(qkv_bf, o_bf);
  // 5) x_attn = v_in + o @ wo + bo  (f32)
  gemm_bf16<2, 1><<<dim3(Ec / 128, Ntok / 128), 512, 0, stream>>>(
      o_bf, wo_t, bo, v_in, x_attn, nullptr, Ntok, Ec, Ec);
  // 6) n2 = LN(x_attn) -> bf16
  k_lnrow<0><<<Ntok, 256, 0, stream>>>(x_attn, ln2_g, ln2_b, nullptr, n2_bf);
  // 7+8 fused) hN = n2 @ (gp_w@gat_w) + gp_b@gat_w -> f32
  gemm_bf16<1, 1><<<dim3(Ec / 128, Ntok / 128), 512, 0, stream>>>(
      n2_bf, gpgat_t, bias2, nullptr, hN, nullptr, Ntok, Ec, Ec);
  // 9) a_s, a_d
  k_asd<<<Ntok / 4, 256, 0, stream>>>(hN, att_src, att_dst, a_s, a_d);
  // 10) GAT aggregate + elu + residual -> x_after
  k_gat<<<Ntok, 256, 0, stream>>>(hN, a_s, a_d, x_attn, gat_b, x_after);
  // 11) n3 = LN(x_after) -> f32 + bf16
  k_lnrow<2><<<Ntok, 256, 0, stream>>>(x_after, ln3_g, ln3_b, n3_f, n3_bf);
  // 12) h1 = gelu(n3 @ mlp_w1 + mlp_b1) -> bf16
  gemm_bf16<3, 2><<<dim3(Ec / 128, Ntok / 128), 512, 0, stream>>>(
      n3_bf, m1_t, mlp_b1, nullptr, nullptr, h1_bf, Ntok, Ec, Ec);
  // 13) mlp = h1 @ mlp_w2 + mlp_b2 -> f32
  gemm_bf16<1, 1><<<dim3(Ec / 128, Ntok / 128), 512, 0, stream>>>(
      h1_bf, m2_t, mlp_b2, nullptr, mlp_out, nullptr, Ntok, Ec, Ec);
  // 14) out = LN(n3 + mlp), transposed to [B,E,H,W]
  k_lnout<<<256, 256, 0, stream>>>(n3_f, mlp_out, fn_g, fn_b, out);
}